// Round 2
// baseline (7944.874 us; speedup 1.0000x reference)
//
#include <hip/hip_runtime.h>

#define DIM 128
#define NLEV 8
#define NB_LVL 256   // persistent kernel: 256 blocks (1/CU -> co-residency guaranteed)

__device__ __forceinline__ int cls_of(int g, int l) {
    if (l < 1 || l > NLEV) return -1;
    if (g == 1) return l - 1;
    if (g == 2) return NLEV + (l - 1);
    return -1;
}

// ---------------- prep kernels ----------------

__global__ void deg_count_kernel(const int* __restrict__ dstv, int* __restrict__ degi, int E) {
    int i = blockIdx.x * blockDim.x + threadIdx.x;
    if (i < E) atomicAdd(&degi[dstv[i]], 1);
}

__global__ void deg_finalize_kernel(const int* __restrict__ degi, float* __restrict__ dis,
                                    float* __restrict__ inv, int n) {
    int i = blockIdx.x * blockDim.x + threadIdx.x;
    if (i < n) {
        float d = (float)degi[i] + 1.0f;
        dis[i] = rsqrtf(d);
        inv[i] = 1.0f / d;
    }
}

// single-block exclusive prefix sum of degi -> offs[0..n], n multiple of 1024
__global__ __launch_bounds__(1024) void prefix_kernel(const int* __restrict__ degi,
                                                      int* __restrict__ offs, int n) {
    __shared__ int part[1024];
    int t = threadIdx.x;
    int chunk = n / 1024;
    int base = t * chunk;
    int s = 0;
    for (int i = 0; i < chunk; i++) s += degi[base + i];
    part[t] = s;
    __syncthreads();
    for (int off = 1; off < 1024; off <<= 1) {
        int v = (t >= off) ? part[t - off] : 0;
        __syncthreads();
        part[t] += v;
        __syncthreads();
    }
    int excl = (t == 0) ? 0 : part[t - 1];
    for (int i = 0; i < chunk; i++) {
        int d = degi[base + i];
        offs[base + i] = excl;
        excl += d;
    }
    if (t == 1023) offs[n] = excl;
}

__global__ void csr_fill_kernel(const int* __restrict__ srcv, const int* __restrict__ dstv,
                                const int* __restrict__ offs, int* __restrict__ cursor,
                                int* __restrict__ csr_src, int E) {
    int i = blockIdx.x * blockDim.x + threadIdx.x;
    if (i >= E) return;
    int d = dstv[i];
    int pos = offs[d] + atomicAdd(&cursor[d], 1);
    csr_src[pos] = srcv[i];
}

// LDS-aggregated class-list build (fixes 16-counter global atomic contention)
__global__ __launch_bounds__(256) void build_node_lists_kernel(const int* __restrict__ gate,
                                                               const int* __restrict__ level,
                                                               int* __restrict__ nlist,
                                                               int* __restrict__ ncnt, int n) {
    __shared__ int lcnt[16];
    __shared__ int lbase[16];
    int t = threadIdx.x;
    int i = blockIdx.x * 256 + t;
    if (t < 16) lcnt[t] = 0;
    __syncthreads();
    int c = -1, lpos = 0;
    if (i < n) {
        c = cls_of(gate[i], level[i]);
        if (c >= 0) lpos = atomicAdd(&lcnt[c], 1);
    }
    __syncthreads();
    if (t < 16 && lcnt[t] > 0) lbase[t] = atomicAdd(&ncnt[t], lcnt[t]);
    __syncthreads();
    if (c >= 0) nlist[c * n + lbase[c] + lpos] = i;
}

// ---------------- dense matmul (row-block per workgroup) ----------------
// out[i][j] = acc + optional bias; ACT 0 none.
template <int BIAS>
__global__ __launch_bounds__(DIM) void mm_kernel(const float* __restrict__ in0,
                                                 const float* __restrict__ W,
                                                 const float* __restrict__ b,
                                                 float* __restrict__ out, int n) {
    const int R = 8;
    int row0 = blockIdx.x * R;
    int j = threadIdx.x;
    float acc[R];
#pragma unroll
    for (int r = 0; r < R; r++) acc[r] = 0.f;
    for (int k = 0; k < DIM; k += 4) {
        float w0 = W[(k + 0) * DIM + j];
        float w1 = W[(k + 1) * DIM + j];
        float w2 = W[(k + 2) * DIM + j];
        float w3 = W[(k + 3) * DIM + j];
#pragma unroll
        for (int r = 0; r < R; r++) {
            const float4 a = *reinterpret_cast<const float4*>(in0 + (size_t)(row0 + r) * DIM + k);
            acc[r] = fmaf(a.x, w0, acc[r]);
            acc[r] = fmaf(a.y, w1, acc[r]);
            acc[r] = fmaf(a.z, w2, acc[r]);
            acc[r] = fmaf(a.w, w3, acc[r]);
        }
    }
    float bias = BIAS ? b[j] : 0.f;
#pragma unroll
    for (int r = 0; r < R; r++) out[(size_t)(row0 + r) * DIM + j] = acc[r] + bias;
}

// ---------------- GCN aggregate as gather (no atomics) ----------------
__global__ __launch_bounds__(256) void gcn_gather_kernel(const float* __restrict__ x,
                                                         const float* __restrict__ dis,
                                                         const float* __restrict__ inv,
                                                         const float* __restrict__ gb,
                                                         const int* __restrict__ offs,
                                                         const int* __restrict__ csr_src,
                                                         float* __restrict__ x2, int n) {
    int slot = threadIdx.x >> 7, j = threadIdx.x & 127;
    for (int node = blockIdx.x * 2 + slot; node < n; node += gridDim.x * 2) {
        float di = dis[node];
        float acc = inv[node] * x[(size_t)node * DIM + j] + gb[j];
        int e1 = offs[node + 1];
        for (int p = offs[node]; p < e1; p++) {
            int s = csr_src[p];
            acc += di * dis[s] * x[(size_t)s * DIM + j];
        }
        x2[(size_t)node * DIM + j] = acc;
    }
}

// ---------------- persistent level-loop kernel ----------------

__device__ __forceinline__ void gbar(int* cnt, int* gen, int nb) {
    __syncthreads();
    if (threadIdx.x == 0) {
        int g = __hip_atomic_load(gen, __ATOMIC_RELAXED, __HIP_MEMORY_SCOPE_AGENT);
        int t = __hip_atomic_fetch_add(cnt, 1, __ATOMIC_ACQ_REL, __HIP_MEMORY_SCOPE_AGENT);
        if (t == nb - 1) {
            __hip_atomic_store(cnt, 0, __ATOMIC_RELAXED, __HIP_MEMORY_SCOPE_AGENT);
            __hip_atomic_store(gen, g + 1, __ATOMIC_RELEASE, __HIP_MEMORY_SCOPE_AGENT);
        } else {
            while (__hip_atomic_load(gen, __ATOMIC_ACQUIRE, __HIP_MEMORY_SCOPE_AGENT) == g) {
                __builtin_amdgcn_s_sleep(2);
            }
        }
    }
    __syncthreads();
}

// sum over in-edges of relu(in0[src]@W[0:128] (+ in1[src]@W[128:256]) + b), column j
template <int NSRC>
__device__ __forceinline__ float gather_msgs(const float* __restrict__ in0,
                                             const float* __restrict__ in1,
                                             const float* __restrict__ W,
                                             const float* __restrict__ b,
                                             const int* __restrict__ csr_src,
                                             int e0, int e1, int j) {
    float acc = 0.f;
    const float bj = b[j];
    for (int p = e0; p < e1; p += 4) {
        const int ne = min(4, e1 - p);
        const int s0 = csr_src[p];
        const int s1 = csr_src[p + (ne > 1 ? 1 : 0)];
        const int s2 = csr_src[p + (ne > 2 ? 2 : 0)];
        const int s3 = csr_src[p + (ne > 3 ? 3 : 0)];
        float m0 = bj, m1 = bj, m2 = bj, m3 = bj;
        {
            const float* r0 = in0 + (size_t)s0 * DIM;
            const float* r1 = in0 + (size_t)s1 * DIM;
            const float* r2 = in0 + (size_t)s2 * DIM;
            const float* r3 = in0 + (size_t)s3 * DIM;
            for (int k = 0; k < DIM; k += 4) {
                const float w0 = W[(k + 0) * DIM + j];
                const float w1 = W[(k + 1) * DIM + j];
                const float w2 = W[(k + 2) * DIM + j];
                const float w3 = W[(k + 3) * DIM + j];
                float4 a;
                a = *(const float4*)(r0 + k);
                m0 = fmaf(a.x, w0, m0); m0 = fmaf(a.y, w1, m0); m0 = fmaf(a.z, w2, m0); m0 = fmaf(a.w, w3, m0);
                a = *(const float4*)(r1 + k);
                m1 = fmaf(a.x, w0, m1); m1 = fmaf(a.y, w1, m1); m1 = fmaf(a.z, w2, m1); m1 = fmaf(a.w, w3, m1);
                a = *(const float4*)(r2 + k);
                m2 = fmaf(a.x, w0, m2); m2 = fmaf(a.y, w1, m2); m2 = fmaf(a.z, w2, m2); m2 = fmaf(a.w, w3, m2);
                a = *(const float4*)(r3 + k);
                m3 = fmaf(a.x, w0, m3); m3 = fmaf(a.y, w1, m3); m3 = fmaf(a.z, w2, m3); m3 = fmaf(a.w, w3, m3);
            }
        }
        if (NSRC == 2) {
            const float* r0 = in1 + (size_t)s0 * DIM;
            const float* r1 = in1 + (size_t)s1 * DIM;
            const float* r2 = in1 + (size_t)s2 * DIM;
            const float* r3 = in1 + (size_t)s3 * DIM;
            for (int k = 0; k < DIM; k += 4) {
                const float w0 = W[(DIM + k + 0) * DIM + j];
                const float w1 = W[(DIM + k + 1) * DIM + j];
                const float w2 = W[(DIM + k + 2) * DIM + j];
                const float w3 = W[(DIM + k + 3) * DIM + j];
                float4 a;
                a = *(const float4*)(r0 + k);
                m0 = fmaf(a.x, w0, m0); m0 = fmaf(a.y, w1, m0); m0 = fmaf(a.z, w2, m0); m0 = fmaf(a.w, w3, m0);
                a = *(const float4*)(r1 + k);
                m1 = fmaf(a.x, w0, m1); m1 = fmaf(a.y, w1, m1); m1 = fmaf(a.z, w2, m1); m1 = fmaf(a.w, w3, m1);
                a = *(const float4*)(r2 + k);
                m2 = fmaf(a.x, w0, m2); m2 = fmaf(a.y, w1, m2); m2 = fmaf(a.z, w2, m2); m2 = fmaf(a.w, w3, m2);
                a = *(const float4*)(r3 + k);
                m3 = fmaf(a.x, w0, m3); m3 = fmaf(a.y, w1, m3); m3 = fmaf(a.z, w2, m3); m3 = fmaf(a.w, w3, m3);
            }
        }
        acc += fmaxf(m0, 0.f);
        if (ne > 1) acc += fmaxf(m1, 0.f);
        if (ne > 2) acc += fmaxf(m2, 0.f);
        if (ne > 3) acc += fmaxf(m3, 0.f);
    }
    return acc;
}

__global__ __launch_bounds__(256) void level_kernel(
        float* __restrict__ hs, float* __restrict__ hf, float* __restrict__ updbuf,
        const int* __restrict__ offs, const int* __restrict__ csr_src,
        const int* __restrict__ nlist, const int* __restrict__ ncnt,
        const float* __restrict__ as_w, const float* __restrict__ as_b,
        const float* __restrict__ ua_w, const float* __restrict__ ua_b,
        const float* __restrict__ af_w, const float* __restrict__ af_b,
        const float* __restrict__ ns_w, const float* __restrict__ ns_b,
        const float* __restrict__ un_w, const float* __restrict__ un_b,
        const float* __restrict__ nf_w, const float* __restrict__ nf_b,
        int* __restrict__ bar, int n) {
    const int slot = threadIdx.x >> 7;
    const int j = threadIdx.x & 127;
    const int nb = gridDim.x;
    const int stride = nb * 2;
    __shared__ float sh[2][DIM];
    int* bcnt = bar;
    int* bgen = bar + 1;

    for (int l = 1; l <= NLEV; l++) {
        const int cA = l - 1;
        const int cN = NLEV + l - 1;

        // ---- stage 1: AND structural: hs[c] = relu(cat[hs, agg] @ ua_w + ua_b) ----
        {
            const int cnt = ncnt[cA];
            const int iters = (cnt + stride - 1) / stride;
            for (int it = 0; it < iters; it++) {
                const int idx = it * stride + blockIdx.x * 2 + slot;
                const bool act = idx < cnt;
                const int node = act ? nlist[cA * n + idx] : 0;
                float agg = 0.f;
                if (act) agg = gather_msgs<1>(hs, nullptr, as_w, as_b, csr_src, offs[node], offs[node + 1], j);
                sh[slot][j] = agg;
                __syncthreads();
                float u = ua_b[j];
                const float* hrow = hs + (size_t)node * DIM;
                for (int k = 0; k < DIM; k += 4) {
                    float4 a = *(const float4*)(hrow + k);
                    u = fmaf(a.x, ua_w[(k + 0) * DIM + j], u);
                    u = fmaf(a.y, ua_w[(k + 1) * DIM + j], u);
                    u = fmaf(a.z, ua_w[(k + 2) * DIM + j], u);
                    u = fmaf(a.w, ua_w[(k + 3) * DIM + j], u);
                    float4 g = *(const float4*)(&sh[slot][k]);
                    u = fmaf(g.x, ua_w[(DIM + k + 0) * DIM + j], u);
                    u = fmaf(g.y, ua_w[(DIM + k + 1) * DIM + j], u);
                    u = fmaf(g.z, ua_w[(DIM + k + 2) * DIM + j], u);
                    u = fmaf(g.w, ua_w[(DIM + k + 3) * DIM + j], u);
                }
                if (act) updbuf[(size_t)idx * DIM + j] = fmaxf(u, 0.f);
                __syncthreads();
            }
            gbar(bcnt, bgen, nb);
            for (int idx = blockIdx.x * 2 + slot; idx < cnt; idx += stride) {
                const int node = nlist[cA * n + idx];
                hs[(size_t)node * DIM + j] = updbuf[(size_t)idx * DIM + j];
            }
            gbar(bcnt, bgen, nb);
        }

        // ---- stage 2: AND functional: hf[c] = sum relu(cat[hs,hf][src] @ af_w + af_b) ----
        {
            const int cnt = ncnt[cA];
            for (int idx = blockIdx.x * 2 + slot; idx < cnt; idx += stride) {
                const int node = nlist[cA * n + idx];
                updbuf[(size_t)idx * DIM + j] =
                    gather_msgs<2>(hs, hf, af_w, af_b, csr_src, offs[node], offs[node + 1], j);
            }
            gbar(bcnt, bgen, nb);
            for (int idx = blockIdx.x * 2 + slot; idx < cnt; idx += stride) {
                const int node = nlist[cA * n + idx];
                hf[(size_t)node * DIM + j] = updbuf[(size_t)idx * DIM + j];
            }
            gbar(bcnt, bgen, nb);
        }

        // ---- stage 3: NOT structural: hs[c] = tanh(agg @ un_w + un_b) ----
        {
            const int cnt = ncnt[cN];
            const int iters = (cnt + stride - 1) / stride;
            for (int it = 0; it < iters; it++) {
                const int idx = it * stride + blockIdx.x * 2 + slot;
                const bool act = idx < cnt;
                const int node = act ? nlist[cN * n + idx] : 0;
                float agg = 0.f;
                if (act) agg = gather_msgs<1>(hs, nullptr, ns_w, ns_b, csr_src, offs[node], offs[node + 1], j);
                sh[slot][j] = agg;
                __syncthreads();
                float u = un_b[j];
                for (int k = 0; k < DIM; k += 4) {
                    float4 g = *(const float4*)(&sh[slot][k]);
                    u = fmaf(g.x, un_w[(k + 0) * DIM + j], u);
                    u = fmaf(g.y, un_w[(k + 1) * DIM + j], u);
                    u = fmaf(g.z, un_w[(k + 2) * DIM + j], u);
                    u = fmaf(g.w, un_w[(k + 3) * DIM + j], u);
                }
                if (act) updbuf[(size_t)idx * DIM + j] = tanhf(u);
                __syncthreads();
            }
            gbar(bcnt, bgen, nb);
            for (int idx = blockIdx.x * 2 + slot; idx < cnt; idx += stride) {
                const int node = nlist[cN * n + idx];
                hs[(size_t)node * DIM + j] = updbuf[(size_t)idx * DIM + j];
            }
            gbar(bcnt, bgen, nb);
        }

        // ---- stage 4: NOT functional: hf[c] = sum relu(hf[src] @ nf_w + nf_b) ----
        {
            const int cnt = ncnt[cN];
            for (int idx = blockIdx.x * 2 + slot; idx < cnt; idx += stride) {
                const int node = nlist[cN * n + idx];
                updbuf[(size_t)idx * DIM + j] =
                    gather_msgs<1>(hf, nullptr, nf_w, nf_b, csr_src, offs[node], offs[node + 1], j);
            }
            gbar(bcnt, bgen, nb);
            for (int idx = blockIdx.x * 2 + slot; idx < cnt; idx += stride) {
                const int node = nlist[cN * n + idx];
                hf[(size_t)node * DIM + j] = updbuf[(size_t)idx * DIM + j];
            }
            gbar(bcnt, bgen, nb);
        }
    }
}

// ---------------- decoder as gather (wave per node, deterministic) ----------------
__global__ __launch_bounds__(256) void dec_gather_kernel(const float* __restrict__ zs,
                                                         const float* __restrict__ zt,
                                                         const int* __restrict__ offs,
                                                         const int* __restrict__ csr_src,
                                                         float* __restrict__ hf_out, int n) {
    int w = threadIdx.x >> 6, lane = threadIdx.x & 63;
    for (int node = blockIdx.x * 4 + w; node < n; node += gridDim.x * 4) {
        float b0 = zt[(size_t)node * DIM + lane];
        float b1 = zt[(size_t)node * DIM + 64 + lane];
        float acc0 = 0.f, acc1 = 0.f;
        int e1 = offs[node + 1];
        for (int p = offs[node]; p < e1; p++) {
            int s = csr_src[p];
            float a0 = zs[(size_t)s * DIM + lane];
            float a1 = zs[(size_t)s * DIM + 64 + lane];
            float pd = a0 * b0 + a1 * b1;
#pragma unroll
            for (int off = 32; off > 0; off >>= 1) pd += __shfl_xor(pd, off, 64);
            float wg = 1.f / (1.f + __expf(-pd));
            acc0 += wg * a0;
            acc1 += wg * a1;
        }
        hf_out[(size_t)node * DIM + lane] = acc0;
        hf_out[(size_t)node * DIM + 64 + lane] = acc1;
    }
}

extern "C" void kernel_launch(void* const* d_in, const int* in_sizes, int n_in,
                              void* d_out, int out_size, void* d_ws, size_t ws_size,
                              hipStream_t stream) {
    const float* hs_init = (const float*)d_in[0];
    const int* ei = (const int*)d_in[1];
    const int* gate = (const int*)d_in[2];
    const int* level = (const int*)d_in[3];
    const float* gcn_w = (const float*)d_in[4];
    const float* gcn_b = (const float*)d_in[5];
    const float* mu_w = (const float*)d_in[6];
    const float* mu_b = (const float*)d_in[7];
    // ls_w/ls_b (d_in[8,9]) dead in eval mode
    const float* as_w = (const float*)d_in[10];
    const float* as_b = (const float*)d_in[11];
    const float* ns_w = (const float*)d_in[12];
    const float* ns_b = (const float*)d_in[13];
    const float* af_w = (const float*)d_in[14];
    const float* af_b = (const float*)d_in[15];
    const float* nf_w = (const float*)d_in[16];
    const float* nf_b = (const float*)d_in[17];
    const float* ua_w = (const float*)d_in[18];
    const float* ua_b = (const float*)d_in[19];
    const float* un_w = (const float*)d_in[20];
    const float* un_b = (const float*)d_in[21];
    const float* dec_ws_w = (const float*)d_in[22];
    const float* dec_wt_w = (const float*)d_in[23];

    const int n = in_sizes[0] / DIM;  // 32768
    const int E = in_sizes[1] / 2;    // 65536
    const int* srcv = ei;
    const int* dstv = ei + E;

    float* hs = (float*)d_out;             // [n, DIM]
    float* hf_out = hs + (size_t)n * DIM;  // [n, DIM]

    char* wp = (char*)d_ws;
    float* x = (float*)wp;   wp += (size_t)n * DIM * 4;   // also updbuf, then zs
    float* x2 = (float*)wp;  wp += (size_t)n * DIM * 4;   // also zt
    float* hf = (float*)wp;  wp += (size_t)n * DIM * 4;
    // small region (memset as one range): degi, cursor, ncnt, bar
    char* small0 = wp;
    int* degi = (int*)wp;    wp += (size_t)n * 4;
    int* cursor = (int*)wp;  wp += (size_t)n * 4;
    int* ncnt = (int*)wp;    wp += 16 * 4;
    int* bar = (int*)wp;     wp += 4 * 4;
    size_t small_bytes = (size_t)(wp - small0);
    int* offs = (int*)wp;    wp += (size_t)(n + 1) * 4;
    int* csr_src = (int*)wp; wp += (size_t)E * 4;
    int* nlist = (int*)wp;   wp += (size_t)16 * n * 4;
    float* dis = (float*)wp; wp += (size_t)n * 4;
    float* inv = (float*)wp; wp += (size_t)n * 4;

    hipMemsetAsync(small0, 0, small_bytes, stream);
    hipMemsetAsync(hf, 0, (size_t)n * DIM * 4, stream);

    deg_count_kernel<<<(E + 255) / 256, 256, 0, stream>>>(dstv, degi, E);
    deg_finalize_kernel<<<(n + 255) / 256, 256, 0, stream>>>(degi, dis, inv, n);
    build_node_lists_kernel<<<(n + 255) / 256, 256, 0, stream>>>(gate, level, nlist, ncnt, n);
    prefix_kernel<<<1, 1024, 0, stream>>>(degi, offs, n);
    csr_fill_kernel<<<(E + 255) / 256, 256, 0, stream>>>(srcv, dstv, offs, cursor, csr_src, E);

    // --- GCN encoder ---
    mm_kernel<0><<<n / 8, DIM, 0, stream>>>(hs_init, gcn_w, nullptr, x, n);
    gcn_gather_kernel<<<2048, 256, 0, stream>>>(x, dis, inv, gcn_b, offs, csr_src, x2, n);
    mm_kernel<1><<<n / 8, DIM, 0, stream>>>(x2, mu_w, mu_b, hs, n);  // hs = mu

    // --- fused level loop (persistent kernel, grid barriers) ---
    level_kernel<<<NB_LVL, 256, 0, stream>>>(hs, hf, /*updbuf=*/x, offs, csr_src, nlist, ncnt,
                                             as_w, as_b, ua_w, ua_b, af_w, af_b,
                                             ns_w, ns_b, un_w, un_b, nf_w, nf_b, bar, n);

    // --- decoder ---
    float* zs = x;
    float* zt = x2;
    mm_kernel<0><<<n / 8, DIM, 0, stream>>>(hs, dec_ws_w, nullptr, zs, n);
    mm_kernel<0><<<n / 8, DIM, 0, stream>>>(hs, dec_wt_w, nullptr, zt, n);
    dec_gather_kernel<<<2048, 256, 0, stream>>>(zs, zt, offs, csr_src, hf_out, n);
}

// Round 3
// 1650.644 us; speedup vs baseline: 4.8132x; 4.8132x over previous
//
#include <hip/hip_runtime.h>

#define DIM 128
#define NLEV 8
#define NB_LVL 256   // persistent kernel: 256 blocks (<=1 per CU -> co-residency guaranteed)
#define TMP_CAP 8192 // rows per tmp class buffer (expected ~1213 per class)

__device__ __forceinline__ int cls_of(int g, int l) {
    if (l < 1 || l > NLEV) return -1;
    if (g == 1) return l - 1;
    if (g == 2) return NLEV + (l - 1);
    return -1;
}

// ---------------- prep kernels ----------------

__global__ void deg_count_kernel(const int* __restrict__ dstv, int* __restrict__ degi, int E) {
    int i = blockIdx.x * blockDim.x + threadIdx.x;
    if (i < E) atomicAdd(&degi[dstv[i]], 1);
}

__global__ void deg_finalize_kernel(const int* __restrict__ degi, float* __restrict__ dis,
                                    float* __restrict__ inv, int n) {
    int i = blockIdx.x * blockDim.x + threadIdx.x;
    if (i < n) {
        float d = (float)degi[i] + 1.0f;
        dis[i] = rsqrtf(d);
        inv[i] = 1.0f / d;
    }
}

// single-block exclusive prefix sum of degi -> offs[0..n], n multiple of 1024
__global__ __launch_bounds__(1024) void prefix_kernel(const int* __restrict__ degi,
                                                      int* __restrict__ offs, int n) {
    __shared__ int part[1024];
    int t = threadIdx.x;
    int chunk = n / 1024;
    int base = t * chunk;
    int s = 0;
    for (int i = 0; i < chunk; i++) s += degi[base + i];
    part[t] = s;
    __syncthreads();
    for (int off = 1; off < 1024; off <<= 1) {
        int v = (t >= off) ? part[t - off] : 0;
        __syncthreads();
        part[t] += v;
        __syncthreads();
    }
    int excl = (t == 0) ? 0 : part[t - 1];
    for (int i = 0; i < chunk; i++) {
        int d = degi[base + i];
        offs[base + i] = excl;
        excl += d;
    }
    if (t == 1023) offs[n] = excl;
}

__global__ void csr_fill_kernel(const int* __restrict__ srcv, const int* __restrict__ dstv,
                                const int* __restrict__ offs, int* __restrict__ cursor,
                                int* __restrict__ csr_src, int E) {
    int i = blockIdx.x * blockDim.x + threadIdx.x;
    if (i >= E) return;
    int d = dstv[i];
    int pos = offs[d] + atomicAdd(&cursor[d], 1);
    csr_src[pos] = srcv[i];
}

// class lists + per-node packed (cls<<16)|idx lookup (clsidx pre-memset to -1)
__global__ __launch_bounds__(256) void build_node_lists_kernel(const int* __restrict__ gate,
                                                               const int* __restrict__ level,
                                                               int* __restrict__ nlist,
                                                               int* __restrict__ ncnt,
                                                               int* __restrict__ clsidx, int n) {
    __shared__ int lcnt[16];
    __shared__ int lbase[16];
    int t = threadIdx.x;
    int i = blockIdx.x * 256 + t;
    if (t < 16) lcnt[t] = 0;
    __syncthreads();
    int c = -1, lpos = 0;
    if (i < n) {
        c = cls_of(gate[i], level[i]);
        if (c >= 0) lpos = atomicAdd(&lcnt[c], 1);
    }
    __syncthreads();
    if (t < 16 && lcnt[t] > 0) lbase[t] = atomicAdd(&ncnt[t], lcnt[t]);
    __syncthreads();
    if (c >= 0) {
        int idx = lbase[c] + lpos;
        nlist[c * n + idx] = i;
        clsidx[i] = (c << 16) | idx;
    }
}

// ---------------- dense matmul (8 rows per workgroup) ----------------
template <int BIAS>
__global__ __launch_bounds__(DIM) void mm_kernel(const float* __restrict__ in0,
                                                 const float* __restrict__ W,
                                                 const float* __restrict__ b,
                                                 float* __restrict__ out, int n) {
    const int R = 8;
    int row0 = blockIdx.x * R;
    int j = threadIdx.x;
    float acc[R];
#pragma unroll
    for (int r = 0; r < R; r++) acc[r] = 0.f;
    for (int k = 0; k < DIM; k += 4) {
        float w0 = W[(k + 0) * DIM + j];
        float w1 = W[(k + 1) * DIM + j];
        float w2 = W[(k + 2) * DIM + j];
        float w3 = W[(k + 3) * DIM + j];
#pragma unroll
        for (int r = 0; r < R; r++) {
            const float4 a = *reinterpret_cast<const float4*>(in0 + (size_t)(row0 + r) * DIM + k);
            acc[r] = fmaf(a.x, w0, acc[r]);
            acc[r] = fmaf(a.y, w1, acc[r]);
            acc[r] = fmaf(a.z, w2, acc[r]);
            acc[r] = fmaf(a.w, w3, acc[r]);
        }
    }
    float bias = BIAS ? b[j] : 0.f;
#pragma unroll
    for (int r = 0; r < R; r++) out[(size_t)(row0 + r) * DIM + j] = acc[r] + bias;
}

// ---------------- GCN aggregate as gather ----------------
__global__ __launch_bounds__(256) void gcn_gather_kernel(const float* __restrict__ x,
                                                         const float* __restrict__ dis,
                                                         const float* __restrict__ inv,
                                                         const float* __restrict__ gb,
                                                         const int* __restrict__ offs,
                                                         const int* __restrict__ csr_src,
                                                         float* __restrict__ x2, int n) {
    int slot = threadIdx.x >> 7, j = threadIdx.x & 127;
    for (int node = blockIdx.x * 2 + slot; node < n; node += gridDim.x * 2) {
        float di = dis[node];
        float acc = inv[node] * x[(size_t)node * DIM + j] + gb[j];
        int e1 = offs[node + 1];
        for (int p = offs[node]; p < e1; p++) {
            int s = csr_src[p];
            acc += di * dis[s] * x[(size_t)s * DIM + j];
        }
        x2[(size_t)node * DIM + j] = acc;
    }
}

// ---------------- grid barrier: relaxed spin, one fence pair per block ----------------
__device__ __forceinline__ void gbar(int* cnt, int* gen, int nb) {
    __syncthreads();
    if (threadIdx.x == 0) {
        __builtin_amdgcn_fence(__ATOMIC_RELEASE, "agent");
        int g = __hip_atomic_load(gen, __ATOMIC_RELAXED, __HIP_MEMORY_SCOPE_AGENT);
        int t = __hip_atomic_fetch_add(cnt, 1, __ATOMIC_RELAXED, __HIP_MEMORY_SCOPE_AGENT);
        if (t == nb - 1) {
            __builtin_amdgcn_fence(__ATOMIC_ACQUIRE, "agent");
            __hip_atomic_store(cnt, 0, __ATOMIC_RELAXED, __HIP_MEMORY_SCOPE_AGENT);
            __hip_atomic_store(gen, g + 1, __ATOMIC_RELEASE, __HIP_MEMORY_SCOPE_AGENT);
        } else {
            while (__hip_atomic_load(gen, __ATOMIC_RELAXED, __HIP_MEMORY_SCOPE_AGENT) == g)
                __builtin_amdgcn_s_sleep(4);
            __builtin_amdgcn_fence(__ATOMIC_ACQUIRE, "agent");
        }
    }
    __syncthreads();
}

// resolve src row: if MERGE and src belongs to class `cls`, read from tmp[idx] instead of base
template <bool MERGE>
__device__ __forceinline__ const float* resolve_row(const float* __restrict__ base,
                                                    const float* __restrict__ tmp,
                                                    const int* __restrict__ clsidx,
                                                    int cls, int s) {
    if (MERGE) {
        int cc = clsidx[s];
        if ((cc >> 16) == cls) return tmp + (size_t)(cc & 0xFFFF) * DIM;
    }
    return base + (size_t)s * DIM;
}

// sum over in-edges of relu(row(src) @ W + b), column j; 4-edge batches for W reuse
template <bool MERGE>
__device__ __forceinline__ float gather_msgs(const float* __restrict__ hs,
                                             const float* __restrict__ tmp,
                                             const int* __restrict__ clsidx, int cls,
                                             const float* __restrict__ W, float bj,
                                             const int* __restrict__ csr_src,
                                             int e0, int e1, int j) {
    float acc = 0.f;
    for (int p = e0; p < e1; p += 4) {
        const int ne = min(4, e1 - p);
        const int s0 = csr_src[p];
        const int s1 = csr_src[p + (ne > 1 ? 1 : 0)];
        const int s2 = csr_src[p + (ne > 2 ? 2 : 0)];
        const int s3 = csr_src[p + (ne > 3 ? 3 : 0)];
        const float* r0 = resolve_row<MERGE>(hs, tmp, clsidx, cls, s0);
        const float* r1 = resolve_row<MERGE>(hs, tmp, clsidx, cls, s1);
        const float* r2 = resolve_row<MERGE>(hs, tmp, clsidx, cls, s2);
        const float* r3 = resolve_row<MERGE>(hs, tmp, clsidx, cls, s3);
        float m0 = bj, m1 = bj, m2 = bj, m3 = bj;
        for (int k = 0; k < DIM; k += 4) {
            const float w0 = W[(k + 0) * DIM + j];
            const float w1 = W[(k + 1) * DIM + j];
            const float w2 = W[(k + 2) * DIM + j];
            const float w3 = W[(k + 3) * DIM + j];
            float4 a;
            a = *(const float4*)(r0 + k);
            m0 = fmaf(a.x, w0, m0); m0 = fmaf(a.y, w1, m0); m0 = fmaf(a.z, w2, m0); m0 = fmaf(a.w, w3, m0);
            a = *(const float4*)(r1 + k);
            m1 = fmaf(a.x, w0, m1); m1 = fmaf(a.y, w1, m1); m1 = fmaf(a.z, w2, m1); m1 = fmaf(a.w, w3, m1);
            a = *(const float4*)(r2 + k);
            m2 = fmaf(a.x, w0, m2); m2 = fmaf(a.y, w1, m2); m2 = fmaf(a.z, w2, m2); m2 = fmaf(a.w, w3, m2);
            a = *(const float4*)(r3 + k);
            m3 = fmaf(a.x, w0, m3); m3 = fmaf(a.y, w1, m3); m3 = fmaf(a.z, w2, m3); m3 = fmaf(a.w, w3, m3);
        }
        acc += fmaxf(m0, 0.f);
        if (ne > 1) acc += fmaxf(m1, 0.f);
        if (ne > 2) acc += fmaxf(m2, 0.f);
        if (ne > 3) acc += fmaxf(m3, 0.f);
    }
    return acc;
}

// persistent level loop: only the hs (structural) path — the level-loop hf is dead code
// (hf never feeds hs; final hf is recomputed by the decoder from hs alone).
__global__ __launch_bounds__(256) void level_kernel(
        float* __restrict__ hs, float* __restrict__ tmpA, float* __restrict__ tmpN,
        const int* __restrict__ offs, const int* __restrict__ csr_src,
        const int* __restrict__ nlist, const int* __restrict__ ncnt,
        const int* __restrict__ clsidx,
        const float* __restrict__ as_w, const float* __restrict__ as_b,
        const float* __restrict__ ua_w, const float* __restrict__ ua_b,
        const float* __restrict__ ns_w, const float* __restrict__ ns_b,
        const float* __restrict__ un_w, const float* __restrict__ un_b,
        int* __restrict__ bar, int n) {
    const int slot = threadIdx.x >> 7;
    const int j = threadIdx.x & 127;
    const int nb = gridDim.x;
    const int stride = nb * 2;
    __shared__ float sh[2][DIM];
    int* bcnt = bar;
    int* bgen = bar + 32;  // separate cache line

    for (int l = 1; l <= NLEV; l++) {
        const int cA = l - 1;
        const int cN = NLEV + l - 1;
        const int cNp = NLEV + l - 2;  // previous level's NOT class (valid for l>=2)

        // ---- pass1: commit tmpN(prev)->hs  ||  s1: AND gather(hs merged w/ tmpN) -> tmpA ----
        {
            if (l >= 2) {
                const int cntp = min(ncnt[cNp], TMP_CAP);
                for (int idx = blockIdx.x * 2 + slot; idx < cntp; idx += stride) {
                    const int node = nlist[cNp * n + idx];
                    hs[(size_t)node * DIM + j] = tmpN[(size_t)idx * DIM + j];
                }
            }
            const int cnt = min(ncnt[cA], TMP_CAP);
            const int iters = (cnt + stride - 1) / stride;
            const float bj_as = as_b[j];
            const float bj_ua = ua_b[j];
            for (int it = 0; it < iters; it++) {
                const int idx = it * stride + blockIdx.x * 2 + slot;
                const bool act = idx < cnt;
                const int node = act ? nlist[cA * n + idx] : 0;
                float agg = 0.f;
                if (act) {
                    if (l >= 2)
                        agg = gather_msgs<true>(hs, tmpN, clsidx, cNp, as_w, bj_as, csr_src,
                                                offs[node], offs[node + 1], j);
                    else
                        agg = gather_msgs<false>(hs, nullptr, clsidx, -9, as_w, bj_as, csr_src,
                                                 offs[node], offs[node + 1], j);
                }
                sh[slot][j] = agg;
                __syncthreads();
                float u = bj_ua;
                const float* hrow = hs + (size_t)node * DIM;  // node in cA: disjoint from cNp commits
                for (int k = 0; k < DIM; k += 4) {
                    float4 a = *(const float4*)(hrow + k);
                    u = fmaf(a.x, ua_w[(k + 0) * DIM + j], u);
                    u = fmaf(a.y, ua_w[(k + 1) * DIM + j], u);
                    u = fmaf(a.z, ua_w[(k + 2) * DIM + j], u);
                    u = fmaf(a.w, ua_w[(k + 3) * DIM + j], u);
                    float4 g = *(const float4*)(&sh[slot][k]);
                    u = fmaf(g.x, ua_w[(DIM + k + 0) * DIM + j], u);
                    u = fmaf(g.y, ua_w[(DIM + k + 1) * DIM + j], u);
                    u = fmaf(g.z, ua_w[(DIM + k + 2) * DIM + j], u);
                    u = fmaf(g.w, ua_w[(DIM + k + 3) * DIM + j], u);
                }
                if (act) tmpA[(size_t)idx * DIM + j] = fmaxf(u, 0.f);
                __syncthreads();
            }
            gbar(bcnt, bgen, nb);
        }

        // ---- pass2: commit tmpA->hs  ||  s3: NOT gather(hs merged w/ tmpA) -> tanh -> tmpN ----
        {
            const int cntA = min(ncnt[cA], TMP_CAP);
            for (int idx = blockIdx.x * 2 + slot; idx < cntA; idx += stride) {
                const int node = nlist[cA * n + idx];
                hs[(size_t)node * DIM + j] = tmpA[(size_t)idx * DIM + j];
            }
            const int cnt = min(ncnt[cN], TMP_CAP);
            const int iters = (cnt + stride - 1) / stride;
            const float bj_ns = ns_b[j];
            const float bj_un = un_b[j];
            for (int it = 0; it < iters; it++) {
                const int idx = it * stride + blockIdx.x * 2 + slot;
                const bool act = idx < cnt;
                const int node = act ? nlist[cN * n + idx] : 0;
                float agg = 0.f;
                if (act)
                    agg = gather_msgs<true>(hs, tmpA, clsidx, cA, ns_w, bj_ns, csr_src,
                                            offs[node], offs[node + 1], j);
                sh[slot][j] = agg;
                __syncthreads();
                float u = bj_un;
                for (int k = 0; k < DIM; k += 4) {
                    float4 g = *(const float4*)(&sh[slot][k]);
                    u = fmaf(g.x, un_w[(k + 0) * DIM + j], u);
                    u = fmaf(g.y, un_w[(k + 1) * DIM + j], u);
                    u = fmaf(g.z, un_w[(k + 2) * DIM + j], u);
                    u = fmaf(g.w, un_w[(k + 3) * DIM + j], u);
                }
                if (act) tmpN[(size_t)idx * DIM + j] = tanhf(u);
                __syncthreads();
            }
            gbar(bcnt, bgen, nb);
        }
    }

    // final: commit last level's tmpN -> hs (same idx distribution as the writes; no races)
    {
        const int cN = 2 * NLEV - 1;
        const int cnt = min(ncnt[cN], TMP_CAP);
        for (int idx = blockIdx.x * 2 + slot; idx < cnt; idx += stride) {
            const int node = nlist[cN * n + idx];
            hs[(size_t)node * DIM + j] = tmpN[(size_t)idx * DIM + j];
        }
    }
}

// ---------------- decoder as gather (wave per node, deterministic) ----------------
__global__ __launch_bounds__(256) void dec_gather_kernel(const float* __restrict__ zs,
                                                         const float* __restrict__ zt,
                                                         const int* __restrict__ offs,
                                                         const int* __restrict__ csr_src,
                                                         float* __restrict__ hf_out, int n) {
    int w = threadIdx.x >> 6, lane = threadIdx.x & 63;
    for (int node = blockIdx.x * 4 + w; node < n; node += gridDim.x * 4) {
        float b0 = zt[(size_t)node * DIM + lane];
        float b1 = zt[(size_t)node * DIM + 64 + lane];
        float acc0 = 0.f, acc1 = 0.f;
        int e1 = offs[node + 1];
        for (int p = offs[node]; p < e1; p++) {
            int s = csr_src[p];
            float a0 = zs[(size_t)s * DIM + lane];
            float a1 = zs[(size_t)s * DIM + 64 + lane];
            float pd = a0 * b0 + a1 * b1;
#pragma unroll
            for (int off = 32; off > 0; off >>= 1) pd += __shfl_xor(pd, off, 64);
            float wg = 1.f / (1.f + __expf(-pd));
            acc0 += wg * a0;
            acc1 += wg * a1;
        }
        hf_out[(size_t)node * DIM + lane] = acc0;
        hf_out[(size_t)node * DIM + 64 + lane] = acc1;
    }
}

extern "C" void kernel_launch(void* const* d_in, const int* in_sizes, int n_in,
                              void* d_out, int out_size, void* d_ws, size_t ws_size,
                              hipStream_t stream) {
    const float* hs_init = (const float*)d_in[0];
    const int* ei = (const int*)d_in[1];
    const int* gate = (const int*)d_in[2];
    const int* level = (const int*)d_in[3];
    const float* gcn_w = (const float*)d_in[4];
    const float* gcn_b = (const float*)d_in[5];
    const float* mu_w = (const float*)d_in[6];
    const float* mu_b = (const float*)d_in[7];
    // ls_w/ls_b (d_in[8,9]) dead in eval mode; af_w/af_b (14,15), nf_w/nf_b (16,17)
    // dead because the level-loop hf never influences hs and the decoder rebuilds hf from hs.
    const float* as_w = (const float*)d_in[10];
    const float* as_b = (const float*)d_in[11];
    const float* ns_w = (const float*)d_in[12];
    const float* ns_b = (const float*)d_in[13];
    const float* ua_w = (const float*)d_in[18];
    const float* ua_b = (const float*)d_in[19];
    const float* un_w = (const float*)d_in[20];
    const float* un_b = (const float*)d_in[21];
    const float* dec_ws_w = (const float*)d_in[22];
    const float* dec_wt_w = (const float*)d_in[23];

    const int n = in_sizes[0] / DIM;  // 32768
    const int E = in_sizes[1] / 2;    // 65536
    const int* srcv = ei;
    const int* dstv = ei + E;

    float* hs = (float*)d_out;             // [n, DIM]
    float* hf_out = hs + (size_t)n * DIM;  // [n, DIM]

    char* wp = (char*)d_ws;
    float* x = (float*)wp;    wp += (size_t)n * DIM * 4;       // gcn tmp, later zs
    float* x2 = (float*)wp;   wp += (size_t)n * DIM * 4;       // gcn tmp, later zt
    float* tmpA = (float*)wp; wp += (size_t)TMP_CAP * DIM * 4; // AND-update staging
    float* tmpN = (float*)wp; wp += (size_t)TMP_CAP * DIM * 4; // NOT-update staging
    // small region (single memset): degi, cursor, ncnt, bar
    char* small0 = wp;
    int* degi = (int*)wp;   wp += (size_t)n * 4;
    int* cursor = (int*)wp; wp += (size_t)n * 4;
    int* ncnt = (int*)wp;   wp += 16 * 4;
    int* bar = (int*)wp;    wp += 64 * 4;  // cnt at +0, gen at +32 (separate lines)
    size_t small_bytes = (size_t)(wp - small0);
    int* offs = (int*)wp;    wp += (size_t)(n + 1) * 4;
    int* csr_src = (int*)wp; wp += (size_t)E * 4;
    int* nlist = (int*)wp;   wp += (size_t)16 * n * 4;
    int* clsidx = (int*)wp;  wp += (size_t)n * 4;
    float* dis = (float*)wp; wp += (size_t)n * 4;
    float* inv = (float*)wp; wp += (size_t)n * 4;

    hipMemsetAsync(small0, 0, small_bytes, stream);
    hipMemsetAsync(clsidx, 0xFF, (size_t)n * 4, stream);

    deg_count_kernel<<<(E + 255) / 256, 256, 0, stream>>>(dstv, degi, E);
    deg_finalize_kernel<<<(n + 255) / 256, 256, 0, stream>>>(degi, dis, inv, n);
    build_node_lists_kernel<<<(n + 255) / 256, 256, 0, stream>>>(gate, level, nlist, ncnt, clsidx, n);
    prefix_kernel<<<1, 1024, 0, stream>>>(degi, offs, n);
    csr_fill_kernel<<<(E + 255) / 256, 256, 0, stream>>>(srcv, dstv, offs, cursor, csr_src, E);

    // --- GCN encoder ---
    mm_kernel<0><<<n / 8, DIM, 0, stream>>>(hs_init, gcn_w, nullptr, x, n);
    gcn_gather_kernel<<<2048, 256, 0, stream>>>(x, dis, inv, gcn_b, offs, csr_src, x2, n);
    mm_kernel<1><<<n / 8, DIM, 0, stream>>>(x2, mu_w, mu_b, hs, n);  // hs = mu

    // --- fused level loop (16 grid barriers total) ---
    level_kernel<<<NB_LVL, 256, 0, stream>>>(hs, tmpA, tmpN, offs, csr_src, nlist, ncnt, clsidx,
                                             as_w, as_b, ua_w, ua_b, ns_w, ns_b, un_w, un_b,
                                             bar, n);

    // --- decoder ---
    float* zs = x;
    float* zt = x2;
    mm_kernel<0><<<n / 8, DIM, 0, stream>>>(hs, dec_ws_w, nullptr, zs, n);
    mm_kernel<0><<<n / 8, DIM, 0, stream>>>(hs, dec_wt_w, nullptr, zt, n);
    dec_gather_kernel<<<2048, 256, 0, stream>>>(zs, zt, offs, csr_src, hf_out, n);
}

// Round 4
// 1197.407 us; speedup vs baseline: 6.6351x; 1.3785x over previous
//
#include <hip/hip_runtime.h>

#define DIM 128
#define NLEV 8
#define TMP_CAP 8192   // rows per tmp class buffer (expected ~1213 per class)
#define NB_STAGE 1024  // stage-kernel grid: 2048 node-slots >> ~1213 per class

__device__ __forceinline__ int cls_of(int g, int l) {
    if (l < 1 || l > NLEV) return -1;
    if (g == 1) return l - 1;
    if (g == 2) return NLEV + (l - 1);
    return -1;
}

// ---------------- prep kernels ----------------

__global__ void deg_count_kernel(const int* __restrict__ dstv, int* __restrict__ degi, int E) {
    int i = blockIdx.x * blockDim.x + threadIdx.x;
    if (i < E) atomicAdd(&degi[dstv[i]], 1);
}

__global__ void deg_finalize_kernel(const int* __restrict__ degi, float* __restrict__ dis,
                                    float* __restrict__ inv, int n) {
    int i = blockIdx.x * blockDim.x + threadIdx.x;
    if (i < n) {
        float d = (float)degi[i] + 1.0f;
        dis[i] = rsqrtf(d);
        inv[i] = 1.0f / d;
    }
}

// single-block exclusive prefix sum of degi -> offs[0..n], n multiple of 1024
__global__ __launch_bounds__(1024) void prefix_kernel(const int* __restrict__ degi,
                                                      int* __restrict__ offs, int n) {
    __shared__ int part[1024];
    int t = threadIdx.x;
    int chunk = n / 1024;
    int base = t * chunk;
    int s = 0;
    for (int i = 0; i < chunk; i++) s += degi[base + i];
    part[t] = s;
    __syncthreads();
    for (int off = 1; off < 1024; off <<= 1) {
        int v = (t >= off) ? part[t - off] : 0;
        __syncthreads();
        part[t] += v;
        __syncthreads();
    }
    int excl = (t == 0) ? 0 : part[t - 1];
    for (int i = 0; i < chunk; i++) {
        int d = degi[base + i];
        offs[base + i] = excl;
        excl += d;
    }
    if (t == 1023) offs[n] = excl;
}

__global__ void csr_fill_kernel(const int* __restrict__ srcv, const int* __restrict__ dstv,
                                const int* __restrict__ offs, int* __restrict__ cursor,
                                int* __restrict__ csr_src, int E) {
    int i = blockIdx.x * blockDim.x + threadIdx.x;
    if (i >= E) return;
    int d = dstv[i];
    int pos = offs[d] + atomicAdd(&cursor[d], 1);
    csr_src[pos] = srcv[i];
}

// class lists + per-node packed (cls<<16)|idx lookup (clsidx pre-memset to -1)
__global__ __launch_bounds__(256) void build_node_lists_kernel(const int* __restrict__ gate,
                                                               const int* __restrict__ level,
                                                               int* __restrict__ nlist,
                                                               int* __restrict__ ncnt,
                                                               int* __restrict__ clsidx, int n) {
    __shared__ int lcnt[16];
    __shared__ int lbase[16];
    int t = threadIdx.x;
    int i = blockIdx.x * 256 + t;
    if (t < 16) lcnt[t] = 0;
    __syncthreads();
    int c = -1, lpos = 0;
    if (i < n) {
        c = cls_of(gate[i], level[i]);
        if (c >= 0) lpos = atomicAdd(&lcnt[c], 1);
    }
    __syncthreads();
    if (t < 16 && lcnt[t] > 0) lbase[t] = atomicAdd(&ncnt[t], lcnt[t]);
    __syncthreads();
    if (c >= 0) {
        int idx = lbase[c] + lpos;
        nlist[c * n + idx] = i;
        clsidx[i] = (c << 16) | idx;
    }
}

// ---------------- dense matmul (16 rows per workgroup) ----------------
template <int BIAS>
__global__ __launch_bounds__(DIM) void mm_kernel(const float* __restrict__ in0,
                                                 const float* __restrict__ W,
                                                 const float* __restrict__ b,
                                                 float* __restrict__ out, int n) {
    const int R = 16;
    int row0 = blockIdx.x * R;
    int j = threadIdx.x;
    float acc[R];
#pragma unroll
    for (int r = 0; r < R; r++) acc[r] = 0.f;
    for (int k = 0; k < DIM; k += 4) {
        float w0 = W[(k + 0) * DIM + j];
        float w1 = W[(k + 1) * DIM + j];
        float w2 = W[(k + 2) * DIM + j];
        float w3 = W[(k + 3) * DIM + j];
#pragma unroll
        for (int r = 0; r < R; r++) {
            const float4 a = *reinterpret_cast<const float4*>(in0 + (size_t)(row0 + r) * DIM + k);
            acc[r] = fmaf(a.x, w0, acc[r]);
            acc[r] = fmaf(a.y, w1, acc[r]);
            acc[r] = fmaf(a.z, w2, acc[r]);
            acc[r] = fmaf(a.w, w3, acc[r]);
        }
    }
    float bias = BIAS ? b[j] : 0.f;
#pragma unroll
    for (int r = 0; r < R; r++) out[(size_t)(row0 + r) * DIM + j] = acc[r] + bias;
}

// ---------------- GCN aggregate as gather ----------------
__global__ __launch_bounds__(256) void gcn_gather_kernel(const float* __restrict__ x,
                                                         const float* __restrict__ dis,
                                                         const float* __restrict__ inv,
                                                         const float* __restrict__ gb,
                                                         const int* __restrict__ offs,
                                                         const int* __restrict__ csr_src,
                                                         float* __restrict__ x2, int n) {
    int slot = threadIdx.x >> 7, j = threadIdx.x & 127;
    for (int node = blockIdx.x * 2 + slot; node < n; node += gridDim.x * 2) {
        float di = dis[node];
        float acc = inv[node] * x[(size_t)node * DIM + j] + gb[j];
        int e1 = offs[node + 1];
        for (int p = offs[node]; p < e1; p++) {
            int s = csr_src[p];
            acc += di * dis[s] * x[(size_t)s * DIM + j];
        }
        x2[(size_t)node * DIM + j] = acc;
    }
}

// resolve src row: if MERGE and src belongs to class `cls`, read from tmp[idx] instead of base
template <bool MERGE>
__device__ __forceinline__ const float* resolve_row(const float* __restrict__ base,
                                                    const float* __restrict__ tmp,
                                                    const int* __restrict__ clsidx,
                                                    int cls, int s) {
    if (MERGE) {
        int cc = clsidx[s];
        if ((cc >> 16) == cls) return tmp + (size_t)(cc & 0xFFFF) * DIM;
    }
    return base + (size_t)s * DIM;
}

// sum over in-edges of relu(row(src) @ W + b), column j; 4-edge batches for W reuse
template <bool MERGE>
__device__ __forceinline__ float gather_msgs(const float* __restrict__ hs,
                                             const float* __restrict__ tmp,
                                             const int* __restrict__ clsidx, int cls,
                                             const float* __restrict__ W, float bj,
                                             const int* __restrict__ csr_src,
                                             int e0, int e1, int j) {
    float acc = 0.f;
    for (int p = e0; p < e1; p += 4) {
        const int ne = min(4, e1 - p);
        const int s0 = csr_src[p];
        const int s1 = csr_src[p + (ne > 1 ? 1 : 0)];
        const int s2 = csr_src[p + (ne > 2 ? 2 : 0)];
        const int s3 = csr_src[p + (ne > 3 ? 3 : 0)];
        const float* r0 = resolve_row<MERGE>(hs, tmp, clsidx, cls, s0);
        const float* r1 = resolve_row<MERGE>(hs, tmp, clsidx, cls, s1);
        const float* r2 = resolve_row<MERGE>(hs, tmp, clsidx, cls, s2);
        const float* r3 = resolve_row<MERGE>(hs, tmp, clsidx, cls, s3);
        float m0 = bj, m1 = bj, m2 = bj, m3 = bj;
        for (int k = 0; k < DIM; k += 4) {
            const float w0 = W[(k + 0) * DIM + j];
            const float w1 = W[(k + 1) * DIM + j];
            const float w2 = W[(k + 2) * DIM + j];
            const float w3 = W[(k + 3) * DIM + j];
            float4 a;
            a = *(const float4*)(r0 + k);
            m0 = fmaf(a.x, w0, m0); m0 = fmaf(a.y, w1, m0); m0 = fmaf(a.z, w2, m0); m0 = fmaf(a.w, w3, m0);
            a = *(const float4*)(r1 + k);
            m1 = fmaf(a.x, w0, m1); m1 = fmaf(a.y, w1, m1); m1 = fmaf(a.z, w2, m1); m1 = fmaf(a.w, w3, m1);
            a = *(const float4*)(r2 + k);
            m2 = fmaf(a.x, w0, m2); m2 = fmaf(a.y, w1, m2); m2 = fmaf(a.z, w2, m2); m2 = fmaf(a.w, w3, m2);
            a = *(const float4*)(r3 + k);
            m3 = fmaf(a.x, w0, m3); m3 = fmaf(a.y, w1, m3); m3 = fmaf(a.z, w2, m3); m3 = fmaf(a.w, w3, m3);
        }
        acc += fmaxf(m0, 0.f);
        if (ne > 1) acc += fmaxf(m1, 0.f);
        if (ne > 2) acc += fmaxf(m2, 0.f);
        if (ne > 3) acc += fmaxf(m3, 0.f);
    }
    return acc;
}

// ---- AND stage (one launch per level): commit tmpN(prev)->hs, then
//      tmpA[idx] = relu(cat[hs[node], sum relu(src@as_w+as_b)] @ ua_w + ua_b)
//      gathers read prev-NOT rows via tmpN indirection (their hs rows are being
//      committed concurrently, but never read from hs -> no race).
template <bool MERGE>
__global__ __launch_bounds__(256) void and_stage_kernel(
        float* __restrict__ hs, const float* __restrict__ tmpN, float* __restrict__ tmpA,
        const int* __restrict__ offs, const int* __restrict__ csr_src,
        const int* __restrict__ nlist, const int* __restrict__ ncnt,
        const int* __restrict__ clsidx,
        const float* __restrict__ as_w, const float* __restrict__ as_b,
        const float* __restrict__ ua_w, const float* __restrict__ ua_b,
        int cA, int cNp, int n) {
    const int slot = threadIdx.x >> 7;
    const int j = threadIdx.x & 127;
    const int stride = gridDim.x * 2;
    __shared__ float sh[2][DIM];

    if (MERGE) {  // commit previous level's NOT updates
        const int cntp = min(ncnt[cNp], TMP_CAP);
        for (int idx = blockIdx.x * 2 + slot; idx < cntp; idx += stride) {
            const int node = nlist[cNp * n + idx];
            hs[(size_t)node * DIM + j] = tmpN[(size_t)idx * DIM + j];
        }
    }
    const int cnt = min(ncnt[cA], TMP_CAP);
    const int iters = (cnt + stride - 1) / stride;
    const float bj_as = as_b[j];
    const float bj_ua = ua_b[j];
    for (int it = 0; it < iters; it++) {
        if (it * stride + blockIdx.x * 2 >= cnt) break;  // block-uniform
        const int idx = it * stride + blockIdx.x * 2 + slot;
        const bool act = idx < cnt;
        const int node = act ? nlist[cA * n + idx] : 0;
        float agg = 0.f;
        if (act)
            agg = gather_msgs<MERGE>(hs, tmpN, clsidx, cNp, as_w, bj_as, csr_src,
                                     offs[node], offs[node + 1], j);
        sh[slot][j] = agg;
        __syncthreads();
        float u = bj_ua;
        const float* hrow = hs + (size_t)node * DIM;  // node in cA: disjoint from cNp commits
        for (int k = 0; k < DIM; k += 4) {
            float4 a = *(const float4*)(hrow + k);
            u = fmaf(a.x, ua_w[(k + 0) * DIM + j], u);
            u = fmaf(a.y, ua_w[(k + 1) * DIM + j], u);
            u = fmaf(a.z, ua_w[(k + 2) * DIM + j], u);
            u = fmaf(a.w, ua_w[(k + 3) * DIM + j], u);
            float4 g = *(const float4*)(&sh[slot][k]);
            u = fmaf(g.x, ua_w[(DIM + k + 0) * DIM + j], u);
            u = fmaf(g.y, ua_w[(DIM + k + 1) * DIM + j], u);
            u = fmaf(g.z, ua_w[(DIM + k + 2) * DIM + j], u);
            u = fmaf(g.w, ua_w[(DIM + k + 3) * DIM + j], u);
        }
        if (act) tmpA[(size_t)idx * DIM + j] = fmaxf(u, 0.f);
        __syncthreads();
    }
}

// ---- NOT stage (one launch per level): commit tmpA(cA)->hs, then
//      tmpN[idx] = tanh( (sum relu(src@ns_w+ns_b)) @ un_w + un_b )
__global__ __launch_bounds__(256) void not_stage_kernel(
        float* __restrict__ hs, const float* __restrict__ tmpA, float* __restrict__ tmpN,
        const int* __restrict__ offs, const int* __restrict__ csr_src,
        const int* __restrict__ nlist, const int* __restrict__ ncnt,
        const int* __restrict__ clsidx,
        const float* __restrict__ ns_w, const float* __restrict__ ns_b,
        const float* __restrict__ un_w, const float* __restrict__ un_b,
        int cA, int cN, int n) {
    const int slot = threadIdx.x >> 7;
    const int j = threadIdx.x & 127;
    const int stride = gridDim.x * 2;
    __shared__ float sh[2][DIM];

    {  // commit this level's AND updates
        const int cntA = min(ncnt[cA], TMP_CAP);
        for (int idx = blockIdx.x * 2 + slot; idx < cntA; idx += stride) {
            const int node = nlist[cA * n + idx];
            hs[(size_t)node * DIM + j] = tmpA[(size_t)idx * DIM + j];
        }
    }
    const int cnt = min(ncnt[cN], TMP_CAP);
    const int iters = (cnt + stride - 1) / stride;
    const float bj_ns = ns_b[j];
    const float bj_un = un_b[j];
    for (int it = 0; it < iters; it++) {
        if (it * stride + blockIdx.x * 2 >= cnt) break;  // block-uniform
        const int idx = it * stride + blockIdx.x * 2 + slot;
        const bool act = idx < cnt;
        const int node = act ? nlist[cN * n + idx] : 0;
        float agg = 0.f;
        if (act)
            agg = gather_msgs<true>(hs, tmpA, clsidx, cA, ns_w, bj_ns, csr_src,
                                    offs[node], offs[node + 1], j);
        sh[slot][j] = agg;
        __syncthreads();
        float u = bj_un;
        for (int k = 0; k < DIM; k += 4) {
            float4 g = *(const float4*)(&sh[slot][k]);
            u = fmaf(g.x, un_w[(k + 0) * DIM + j], u);
            u = fmaf(g.y, un_w[(k + 1) * DIM + j], u);
            u = fmaf(g.z, un_w[(k + 2) * DIM + j], u);
            u = fmaf(g.w, un_w[(k + 3) * DIM + j], u);
        }
        if (act) tmpN[(size_t)idx * DIM + j] = tanhf(u);
        __syncthreads();
    }
}

// final commit of last level's tmpN -> hs
__global__ __launch_bounds__(256) void commit_kernel(float* __restrict__ hs,
                                                     const float* __restrict__ tmp,
                                                     const int* __restrict__ nlist,
                                                     const int* __restrict__ ncnt,
                                                     int c, int n) {
    const int slot = threadIdx.x >> 7;
    const int j = threadIdx.x & 127;
    const int stride = gridDim.x * 2;
    const int cnt = min(ncnt[c], TMP_CAP);
    for (int idx = blockIdx.x * 2 + slot; idx < cnt; idx += stride) {
        const int node = nlist[c * n + idx];
        hs[(size_t)node * DIM + j] = tmp[(size_t)idx * DIM + j];
    }
}

// ---------------- decoder as gather (wave per node, deterministic) ----------------
__global__ __launch_bounds__(256) void dec_gather_kernel(const float* __restrict__ zs,
                                                         const float* __restrict__ zt,
                                                         const int* __restrict__ offs,
                                                         const int* __restrict__ csr_src,
                                                         float* __restrict__ hf_out, int n) {
    int w = threadIdx.x >> 6, lane = threadIdx.x & 63;
    for (int node = blockIdx.x * 4 + w; node < n; node += gridDim.x * 4) {
        float b0 = zt[(size_t)node * DIM + lane];
        float b1 = zt[(size_t)node * DIM + 64 + lane];
        float acc0 = 0.f, acc1 = 0.f;
        int e1 = offs[node + 1];
        for (int p = offs[node]; p < e1; p++) {
            int s = csr_src[p];
            float a0 = zs[(size_t)s * DIM + lane];
            float a1 = zs[(size_t)s * DIM + 64 + lane];
            float pd = a0 * b0 + a1 * b1;
#pragma unroll
            for (int off = 32; off > 0; off >>= 1) pd += __shfl_xor(pd, off, 64);
            float wg = 1.f / (1.f + __expf(-pd));
            acc0 += wg * a0;
            acc1 += wg * a1;
        }
        hf_out[(size_t)node * DIM + lane] = acc0;
        hf_out[(size_t)node * DIM + 64 + lane] = acc1;
    }
}

extern "C" void kernel_launch(void* const* d_in, const int* in_sizes, int n_in,
                              void* d_out, int out_size, void* d_ws, size_t ws_size,
                              hipStream_t stream) {
    const float* hs_init = (const float*)d_in[0];
    const int* ei = (const int*)d_in[1];
    const int* gate = (const int*)d_in[2];
    const int* level = (const int*)d_in[3];
    const float* gcn_w = (const float*)d_in[4];
    const float* gcn_b = (const float*)d_in[5];
    const float* mu_w = (const float*)d_in[6];
    const float* mu_b = (const float*)d_in[7];
    // ls_w/ls_b (d_in[8,9]) dead in eval mode; af_w/af_b (14,15), nf_w/nf_b (16,17)
    // dead because the level-loop hf never influences hs and the decoder rebuilds hf from hs.
    const float* as_w = (const float*)d_in[10];
    const float* as_b = (const float*)d_in[11];
    const float* ns_w = (const float*)d_in[12];
    const float* ns_b = (const float*)d_in[13];
    const float* ua_w = (const float*)d_in[18];
    const float* ua_b = (const float*)d_in[19];
    const float* un_w = (const float*)d_in[20];
    const float* un_b = (const float*)d_in[21];
    const float* dec_ws_w = (const float*)d_in[22];
    const float* dec_wt_w = (const float*)d_in[23];

    const int n = in_sizes[0] / DIM;  // 32768
    const int E = in_sizes[1] / 2;    // 65536
    const int* srcv = ei;
    const int* dstv = ei + E;

    float* hs = (float*)d_out;             // [n, DIM]
    float* hf_out = hs + (size_t)n * DIM;  // [n, DIM]

    char* wp = (char*)d_ws;
    float* x = (float*)wp;    wp += (size_t)n * DIM * 4;       // gcn tmp, later zs
    float* x2 = (float*)wp;   wp += (size_t)n * DIM * 4;       // gcn tmp, later zt
    float* tmpA = (float*)wp; wp += (size_t)TMP_CAP * DIM * 4; // AND-update staging
    float* tmpN = (float*)wp; wp += (size_t)TMP_CAP * DIM * 4; // NOT-update staging
    // small region (single memset): degi, cursor, ncnt
    char* small0 = wp;
    int* degi = (int*)wp;   wp += (size_t)n * 4;
    int* cursor = (int*)wp; wp += (size_t)n * 4;
    int* ncnt = (int*)wp;   wp += 16 * 4;
    size_t small_bytes = (size_t)(wp - small0);
    int* offs = (int*)wp;    wp += (size_t)(n + 1) * 4;
    int* csr_src = (int*)wp; wp += (size_t)E * 4;
    int* nlist = (int*)wp;   wp += (size_t)16 * n * 4;
    int* clsidx = (int*)wp;  wp += (size_t)n * 4;
    float* dis = (float*)wp; wp += (size_t)n * 4;
    float* inv = (float*)wp; wp += (size_t)n * 4;

    hipMemsetAsync(small0, 0, small_bytes, stream);
    hipMemsetAsync(clsidx, 0xFF, (size_t)n * 4, stream);

    deg_count_kernel<<<(E + 255) / 256, 256, 0, stream>>>(dstv, degi, E);
    deg_finalize_kernel<<<(n + 255) / 256, 256, 0, stream>>>(degi, dis, inv, n);
    build_node_lists_kernel<<<(n + 255) / 256, 256, 0, stream>>>(gate, level, nlist, ncnt, clsidx, n);
    prefix_kernel<<<1, 1024, 0, stream>>>(degi, offs, n);
    csr_fill_kernel<<<(E + 255) / 256, 256, 0, stream>>>(srcv, dstv, offs, cursor, csr_src, E);

    // --- GCN encoder ---
    mm_kernel<0><<<n / 16, DIM, 0, stream>>>(hs_init, gcn_w, nullptr, x, n);
    gcn_gather_kernel<<<2048, 256, 0, stream>>>(x, dis, inv, gcn_b, offs, csr_src, x2, n);
    mm_kernel<1><<<n / 16, DIM, 0, stream>>>(x2, mu_w, mu_b, hs, n);  // hs = mu

    // --- level loop: 2 launches per level; kernel boundary = device-wide barrier ---
    for (int l = 1; l <= NLEV; l++) {
        const int cA = l - 1;
        const int cN = NLEV + l - 1;
        const int cNp = NLEV + l - 2;
        if (l == 1)
            and_stage_kernel<false><<<NB_STAGE, 256, 0, stream>>>(
                hs, tmpN, tmpA, offs, csr_src, nlist, ncnt, clsidx,
                as_w, as_b, ua_w, ua_b, cA, -9, n);
        else
            and_stage_kernel<true><<<NB_STAGE, 256, 0, stream>>>(
                hs, tmpN, tmpA, offs, csr_src, nlist, ncnt, clsidx,
                as_w, as_b, ua_w, ua_b, cA, cNp, n);
        not_stage_kernel<<<NB_STAGE, 256, 0, stream>>>(
            hs, tmpA, tmpN, offs, csr_src, nlist, ncnt, clsidx,
            ns_w, ns_b, un_w, un_b, cA, cN, n);
    }
    commit_kernel<<<NB_STAGE, 256, 0, stream>>>(hs, tmpN, nlist, ncnt, 2 * NLEV - 1, n);

    // --- decoder ---
    float* zs = x;
    float* zt = x2;
    mm_kernel<0><<<n / 16, DIM, 0, stream>>>(hs, dec_ws_w, nullptr, zs, n);
    mm_kernel<0><<<n / 16, DIM, 0, stream>>>(hs, dec_wt_w, nullptr, zt, n);
    dec_gather_kernel<<<2048, 256, 0, stream>>>(zs, zt, offs, csr_src, hf_out, n);
}

// Round 5
// 916.172 us; speedup vs baseline: 8.6718x; 1.3070x over previous
//
#include <hip/hip_runtime.h>

#define DIM 128
#define NLEV 8
#define NB_STAGE 512           // stage-kernel grid; 4 waves/block -> 2048 wave-slots
#define NSLOT (NB_STAGE * 4)
#define AU_CAP (2 * NSLOT)     // A-update coverage (2 fixed iterations)

__device__ __forceinline__ int cls_of(int g, int l) {
    if (l < 1 || l > NLEV) return -1;
    if (g == 1) return l - 1;
    if (g == 2) return NLEV + (l - 1);
    return -1;
}

// ---------------- prep kernels ----------------

__global__ void deg_count_kernel(const int* __restrict__ dstv, int* __restrict__ degi, int E) {
    int i = blockIdx.x * blockDim.x + threadIdx.x;
    if (i < E) atomicAdd(&degi[dstv[i]], 1);
}

__global__ void deg_finalize_kernel(const int* __restrict__ degi, float* __restrict__ dis,
                                    float* __restrict__ inv, int n) {
    int i = blockIdx.x * blockDim.x + threadIdx.x;
    if (i < n) {
        float d = (float)degi[i] + 1.0f;
        dis[i] = rsqrtf(d);
        inv[i] = 1.0f / d;
    }
}

// single-block exclusive prefix sum of degi -> offs[0..n], n multiple of 1024
__global__ __launch_bounds__(1024) void prefix_kernel(const int* __restrict__ degi,
                                                      int* __restrict__ offs, int n) {
    __shared__ int part[1024];
    int t = threadIdx.x;
    int chunk = n / 1024;
    int base = t * chunk;
    int s = 0;
    for (int i = 0; i < chunk; i++) s += degi[base + i];
    part[t] = s;
    __syncthreads();
    for (int off = 1; off < 1024; off <<= 1) {
        int v = (t >= off) ? part[t - off] : 0;
        __syncthreads();
        part[t] += v;
        __syncthreads();
    }
    int excl = (t == 0) ? 0 : part[t - 1];
    for (int i = 0; i < chunk; i++) {
        int d = degi[base + i];
        offs[base + i] = excl;
        excl += d;
    }
    if (t == 1023) offs[n] = excl;
}

__global__ void csr_fill_kernel(const int* __restrict__ srcv, const int* __restrict__ dstv,
                                const int* __restrict__ offs, int* __restrict__ cursor,
                                int* __restrict__ csr_src, int E) {
    int i = blockIdx.x * blockDim.x + threadIdx.x;
    if (i >= E) return;
    int d = dstv[i];
    int pos = offs[d] + atomicAdd(&cursor[d], 1);
    csr_src[pos] = srcv[i];
}

__global__ __launch_bounds__(256) void build_node_lists_kernel(const int* __restrict__ gate,
                                                               const int* __restrict__ level,
                                                               int* __restrict__ nlist,
                                                               int* __restrict__ ncnt, int n) {
    __shared__ int lcnt[16];
    __shared__ int lbase[16];
    int t = threadIdx.x;
    int i = blockIdx.x * 256 + t;
    if (t < 16) lcnt[t] = 0;
    __syncthreads();
    int c = -1, lpos = 0;
    if (i < n) {
        c = cls_of(gate[i], level[i]);
        if (c >= 0) lpos = atomicAdd(&lcnt[c], 1);
    }
    __syncthreads();
    if (t < 16 && lcnt[t] > 0) lbase[t] = atomicAdd(&ncnt[t], lcnt[t]);
    __syncthreads();
    if (c >= 0) nlist[c * n + lbase[c] + lpos] = i;
}

// ---------------- dense matmul (16 rows per workgroup) ----------------
template <int BIAS>
__global__ __launch_bounds__(DIM) void mm_kernel(const float* __restrict__ in0,
                                                 const float* __restrict__ W,
                                                 const float* __restrict__ b,
                                                 float* __restrict__ out, int n) {
    const int R = 16;
    int row0 = blockIdx.x * R;
    int j = threadIdx.x;
    float acc[R];
#pragma unroll
    for (int r = 0; r < R; r++) acc[r] = 0.f;
    for (int k = 0; k < DIM; k += 4) {
        float w0 = W[(k + 0) * DIM + j];
        float w1 = W[(k + 1) * DIM + j];
        float w2 = W[(k + 2) * DIM + j];
        float w3 = W[(k + 3) * DIM + j];
#pragma unroll
        for (int r = 0; r < R; r++) {
            const float4 a = *reinterpret_cast<const float4*>(in0 + (size_t)(row0 + r) * DIM + k);
            acc[r] = fmaf(a.x, w0, acc[r]);
            acc[r] = fmaf(a.y, w1, acc[r]);
            acc[r] = fmaf(a.z, w2, acc[r]);
            acc[r] = fmaf(a.w, w3, acc[r]);
        }
    }
    float bias = BIAS ? b[j] : 0.f;
#pragma unroll
    for (int r = 0; r < R; r++) out[(size_t)(row0 + r) * DIM + j] = acc[r] + bias;
}

// ---------------- GCN aggregate as gather ----------------
__global__ __launch_bounds__(256) void gcn_gather_kernel(const float* __restrict__ x,
                                                         const float* __restrict__ dis,
                                                         const float* __restrict__ inv,
                                                         const float* __restrict__ gb,
                                                         const int* __restrict__ offs,
                                                         const int* __restrict__ csr_src,
                                                         float* __restrict__ x2, int n) {
    int slot = threadIdx.x >> 7, j = threadIdx.x & 127;
    for (int node = blockIdx.x * 2 + slot; node < n; node += gridDim.x * 2) {
        float di = dis[node];
        float acc = inv[node] * x[(size_t)node * DIM + j] + gb[j];
        int e1 = offs[node + 1];
        for (int p = offs[node]; p < e1; p++) {
            int s = csr_src[p];
            acc += di * dis[s] * x[(size_t)s * DIM + j];
        }
        x2[(size_t)node * DIM + j] = acc;
    }
}

// ---------------- level-stage kernels: wave-per-node, W staged in LDS ----------------

// pack a 128x128 W into LDS as float2: W2[k*64+jl] = (W[k][jl], W[k][jl+64])
__device__ __forceinline__ void stage_w128(const float* __restrict__ W, float2* __restrict__ W2) {
    for (int t = threadIdx.x; t < 128 * 64; t += 256) {
        int k = t >> 6, jl = t & 63;
        W2[t] = make_float2(W[k * DIM + jl], W[k * DIM + jl + 64]);
    }
}

// aggbuf[idx] = sum over in-edges(node) of relu(hs[src] @ W + b), node = nlist[c][idx]
__global__ __launch_bounds__(256) void gather_kernel(const float* __restrict__ hs,
                                                     const float* __restrict__ W,
                                                     const float* __restrict__ b,
                                                     const int* __restrict__ offs,
                                                     const int* __restrict__ csr_src,
                                                     const int* __restrict__ nlist,
                                                     const int* __restrict__ ncnt,
                                                     float* __restrict__ aggbuf, int c, int n) {
    __shared__ float2 W2[128 * 64];
    stage_w128(W, W2);
    __syncthreads();
    const int lane = threadIdx.x & 63;
    const int slot = (blockIdx.x << 2) | (threadIdx.x >> 6);
    const int cnt = ncnt[c];
    const float bj0 = b[lane], bj1 = b[lane + 64];
    for (int idx = slot; idx < cnt; idx += NSLOT) {
        const int node = nlist[c * n + idx];
        const int e0 = offs[node], e1 = offs[node + 1];
        float acc0 = 0.f, acc1 = 0.f;
        for (int p = e0; p < e1; p += 2) {
            const bool two = (p + 1 < e1);
            const int s0 = csr_src[p];
            const int s1 = two ? csr_src[p + 1] : s0;
            const float* r0 = hs + (size_t)s0 * DIM;
            const float* r1 = hs + (size_t)s1 * DIM;
            // one coalesced 512B row read per edge (both issued together)
            float a00 = r0[lane], a01 = r0[lane + 64];
            float a10 = r1[lane], a11 = r1[lane + 64];
            float m00 = bj0, m01 = bj1, m10 = bj0, m11 = bj1;
#pragma unroll 8
            for (int k = 0; k < 64; k++) {
                float2 w = W2[k * 64 + lane];
                float v0 = __shfl(a00, k, 64);
                float v1 = __shfl(a10, k, 64);
                m00 = fmaf(v0, w.x, m00); m01 = fmaf(v0, w.y, m01);
                m10 = fmaf(v1, w.x, m10); m11 = fmaf(v1, w.y, m11);
            }
#pragma unroll 8
            for (int k = 0; k < 64; k++) {
                float2 w = W2[(k + 64) * 64 + lane];
                float v0 = __shfl(a01, k, 64);
                float v1 = __shfl(a11, k, 64);
                m00 = fmaf(v0, w.x, m00); m01 = fmaf(v0, w.y, m01);
                m10 = fmaf(v1, w.x, m10); m11 = fmaf(v1, w.y, m11);
            }
            acc0 += fmaxf(m00, 0.f);
            acc1 += fmaxf(m01, 0.f);
            if (two) { acc0 += fmaxf(m10, 0.f); acc1 += fmaxf(m11, 0.f); }
        }
        aggbuf[(size_t)idx * DIM + lane] = acc0;
        aggbuf[(size_t)idx * DIM + lane + 64] = acc1;
    }
}

// hs[node] = relu( cat[hs[node], aggbuf[idx]] @ W(256x128) + b ), two-phase LDS restage
__global__ __launch_bounds__(256) void upd_and_kernel(float* __restrict__ hs,
                                                      const float* __restrict__ aggbuf,
                                                      const float* __restrict__ W,
                                                      const float* __restrict__ b,
                                                      const int* __restrict__ nlist,
                                                      const int* __restrict__ ncnt, int c, int n) {
    __shared__ float2 W2[128 * 64];
    const int lane = threadIdx.x & 63;
    const int slot0 = (blockIdx.x << 2) | (threadIdx.x >> 6);
    const int cnt = min(ncnt[c], AU_CAP);
    const float bj0 = b[lane], bj1 = b[lane + 64];
    int node[2]; bool act[2];
    float h0[2], h1[2], g0[2], g1[2], u0[2], u1[2];
#pragma unroll
    for (int it = 0; it < 2; it++) {
        const int idx = slot0 + it * NSLOT;
        act[it] = idx < cnt;
        node[it] = act[it] ? nlist[c * n + idx] : 0;
        const float* hr = hs + (size_t)node[it] * DIM;
        const float* gr = aggbuf + (size_t)idx * DIM;   // idx < AU_CAP: in-bounds scratch
        h0[it] = hr[lane]; h1[it] = hr[lane + 64];
        g0[it] = gr[lane]; g1[it] = gr[lane + 64];
        u0[it] = bj0; u1[it] = bj1;
    }
    stage_w128(W, W2);          // rows 0..127 (hs half)
    __syncthreads();
#pragma unroll
    for (int it = 0; it < 2; it++) {
#pragma unroll 8
        for (int k = 0; k < 64; k++) {
            float2 w = W2[k * 64 + lane];
            float v = __shfl(h0[it], k, 64);
            u0[it] = fmaf(v, w.x, u0[it]); u1[it] = fmaf(v, w.y, u1[it]);
        }
#pragma unroll 8
        for (int k = 0; k < 64; k++) {
            float2 w = W2[(k + 64) * 64 + lane];
            float v = __shfl(h1[it], k, 64);
            u0[it] = fmaf(v, w.x, u0[it]); u1[it] = fmaf(v, w.y, u1[it]);
        }
    }
    __syncthreads();
    stage_w128(W + 128 * DIM, W2);  // rows 128..255 (agg half)
    __syncthreads();
#pragma unroll
    for (int it = 0; it < 2; it++) {
#pragma unroll 8
        for (int k = 0; k < 64; k++) {
            float2 w = W2[k * 64 + lane];
            float v = __shfl(g0[it], k, 64);
            u0[it] = fmaf(v, w.x, u0[it]); u1[it] = fmaf(v, w.y, u1[it]);
        }
#pragma unroll 8
        for (int k = 0; k < 64; k++) {
            float2 w = W2[(k + 64) * 64 + lane];
            float v = __shfl(g1[it], k, 64);
            u0[it] = fmaf(v, w.x, u0[it]); u1[it] = fmaf(v, w.y, u1[it]);
        }
        if (act[it]) {
            hs[(size_t)node[it] * DIM + lane] = fmaxf(u0[it], 0.f);
            hs[(size_t)node[it] * DIM + lane + 64] = fmaxf(u1[it], 0.f);
        }
    }
}

// hs[node] = tanh( aggbuf[idx] @ W(128x128) + b )
__global__ __launch_bounds__(256) void upd_not_kernel(float* __restrict__ hs,
                                                      const float* __restrict__ aggbuf,
                                                      const float* __restrict__ W,
                                                      const float* __restrict__ b,
                                                      const int* __restrict__ nlist,
                                                      const int* __restrict__ ncnt, int c, int n) {
    __shared__ float2 W2[128 * 64];
    stage_w128(W, W2);
    __syncthreads();
    const int lane = threadIdx.x & 63;
    const int slot = (blockIdx.x << 2) | (threadIdx.x >> 6);
    const int cnt = ncnt[c];
    const float bj0 = b[lane], bj1 = b[lane + 64];
    for (int idx = slot; idx < cnt; idx += NSLOT) {
        const int node = nlist[c * n + idx];
        const float* gr = aggbuf + (size_t)idx * DIM;
        float g0 = gr[lane], g1 = gr[lane + 64];
        float u0 = bj0, u1 = bj1;
#pragma unroll 8
        for (int k = 0; k < 64; k++) {
            float2 w = W2[k * 64 + lane];
            float v = __shfl(g0, k, 64);
            u0 = fmaf(v, w.x, u0); u1 = fmaf(v, w.y, u1);
        }
#pragma unroll 8
        for (int k = 0; k < 64; k++) {
            float2 w = W2[(k + 64) * 64 + lane];
            float v = __shfl(g1, k, 64);
            u0 = fmaf(v, w.x, u0); u1 = fmaf(v, w.y, u1);
        }
        hs[(size_t)node * DIM + lane] = tanhf(u0);
        hs[(size_t)node * DIM + lane + 64] = tanhf(u1);
    }
}

// ---------------- decoder as gather (wave per node, deterministic) ----------------
__global__ __launch_bounds__(256) void dec_gather_kernel(const float* __restrict__ zs,
                                                         const float* __restrict__ zt,
                                                         const int* __restrict__ offs,
                                                         const int* __restrict__ csr_src,
                                                         float* __restrict__ hf_out, int n) {
    int w = threadIdx.x >> 6, lane = threadIdx.x & 63;
    for (int node = blockIdx.x * 4 + w; node < n; node += gridDim.x * 4) {
        float b0 = zt[(size_t)node * DIM + lane];
        float b1 = zt[(size_t)node * DIM + 64 + lane];
        float acc0 = 0.f, acc1 = 0.f;
        int e1 = offs[node + 1];
        for (int p = offs[node]; p < e1; p++) {
            int s = csr_src[p];
            float a0 = zs[(size_t)s * DIM + lane];
            float a1 = zs[(size_t)s * DIM + 64 + lane];
            float pd = a0 * b0 + a1 * b1;
#pragma unroll
            for (int off = 32; off > 0; off >>= 1) pd += __shfl_xor(pd, off, 64);
            float wg = 1.f / (1.f + __expf(-pd));
            acc0 += wg * a0;
            acc1 += wg * a1;
        }
        hf_out[(size_t)node * DIM + lane] = acc0;
        hf_out[(size_t)node * DIM + 64 + lane] = acc1;
    }
}

extern "C" void kernel_launch(void* const* d_in, const int* in_sizes, int n_in,
                              void* d_out, int out_size, void* d_ws, size_t ws_size,
                              hipStream_t stream) {
    const float* hs_init = (const float*)d_in[0];
    const int* ei = (const int*)d_in[1];
    const int* gate = (const int*)d_in[2];
    const int* level = (const int*)d_in[3];
    const float* gcn_w = (const float*)d_in[4];
    const float* gcn_b = (const float*)d_in[5];
    const float* mu_w = (const float*)d_in[6];
    const float* mu_b = (const float*)d_in[7];
    // ls_w/ls_b (8,9) dead (eval mode); af/nf (14..17) dead (level-loop hf never feeds hs;
    // decoder rebuilds hf from hs alone).
    const float* as_w = (const float*)d_in[10];
    const float* as_b = (const float*)d_in[11];
    const float* ns_w = (const float*)d_in[12];
    const float* ns_b = (const float*)d_in[13];
    const float* ua_w = (const float*)d_in[18];
    const float* ua_b = (const float*)d_in[19];
    const float* un_w = (const float*)d_in[20];
    const float* un_b = (const float*)d_in[21];
    const float* dec_ws_w = (const float*)d_in[22];
    const float* dec_wt_w = (const float*)d_in[23];

    const int n = in_sizes[0] / DIM;  // 32768
    const int E = in_sizes[1] / 2;    // 65536
    const int* srcv = ei;
    const int* dstv = ei + E;

    float* hs = (float*)d_out;             // [n, DIM]
    float* hf_out = hs + (size_t)n * DIM;  // [n, DIM]

    char* wp = (char*)d_ws;
    float* x = (float*)wp;      wp += (size_t)n * DIM * 4;        // gcn tmp, later zs
    float* x2 = (float*)wp;     wp += (size_t)n * DIM * 4;        // gcn tmp, later zt
    float* aggbuf = (float*)wp; wp += (size_t)AU_CAP * DIM * 4;   // per-class agg staging
    char* small0 = wp;
    int* degi = (int*)wp;   wp += (size_t)n * 4;
    int* cursor = (int*)wp; wp += (size_t)n * 4;
    int* ncnt = (int*)wp;   wp += 16 * 4;
    size_t small_bytes = (size_t)(wp - small0);
    int* offs = (int*)wp;    wp += (size_t)(n + 1) * 4;
    int* csr_src = (int*)wp; wp += (size_t)E * 4;
    int* nlist = (int*)wp;   wp += (size_t)16 * n * 4;
    float* dis = (float*)wp; wp += (size_t)n * 4;
    float* inv = (float*)wp; wp += (size_t)n * 4;

    hipMemsetAsync(small0, 0, small_bytes, stream);

    deg_count_kernel<<<(E + 255) / 256, 256, 0, stream>>>(dstv, degi, E);
    deg_finalize_kernel<<<(n + 255) / 256, 256, 0, stream>>>(degi, dis, inv, n);
    build_node_lists_kernel<<<(n + 255) / 256, 256, 0, stream>>>(gate, level, nlist, ncnt, n);
    prefix_kernel<<<1, 1024, 0, stream>>>(degi, offs, n);
    csr_fill_kernel<<<(E + 255) / 256, 256, 0, stream>>>(srcv, dstv, offs, cursor, csr_src, E);

    // --- GCN encoder ---
    mm_kernel<0><<<n / 16, DIM, 0, stream>>>(hs_init, gcn_w, nullptr, x, n);
    gcn_gather_kernel<<<2048, 256, 0, stream>>>(x, dis, inv, gcn_b, offs, csr_src, x2, n);
    mm_kernel<1><<<n / 16, DIM, 0, stream>>>(x2, mu_w, mu_b, hs, n);  // hs = mu

    // --- level loop: 4 launches/level, direct hs commits, kernel boundary = barrier ---
    for (int l = 1; l <= NLEV; l++) {
        const int cA = l - 1;
        const int cN = NLEV + l - 1;
        gather_kernel<<<NB_STAGE, 256, 0, stream>>>(hs, as_w, as_b, offs, csr_src, nlist, ncnt,
                                                    aggbuf, cA, n);
        upd_and_kernel<<<NB_STAGE, 256, 0, stream>>>(hs, aggbuf, ua_w, ua_b, nlist, ncnt, cA, n);
        gather_kernel<<<NB_STAGE, 256, 0, stream>>>(hs, ns_w, ns_b, offs, csr_src, nlist, ncnt,
                                                    aggbuf, cN, n);
        upd_not_kernel<<<NB_STAGE, 256, 0, stream>>>(hs, aggbuf, un_w, un_b, nlist, ncnt, cN, n);
    }

    // --- decoder ---
    float* zs = x;
    float* zt = x2;
    mm_kernel<0><<<n / 16, DIM, 0, stream>>>(hs, dec_ws_w, nullptr, zs, n);
    mm_kernel<0><<<n / 16, DIM, 0, stream>>>(hs, dec_wt_w, nullptr, zt, n);
    dec_gather_kernel<<<2048, 256, 0, stream>>>(zs, zt, offs, csr_src, hf_out, n);
}

// Round 6
// 787.660 us; speedup vs baseline: 10.0867x; 1.1632x over previous
//
#include <hip/hip_runtime.h>

#define DIM 128
#define NLEV 8
#define NB_STAGE 512           // stage-kernel grid; 4 waves/block -> 2048 wave-slots
#define NSLOT (NB_STAGE * 4)
#define CAP (2 * NSLOT)        // max nodes per class handled (expected ~1213, 24 sigma safe)

__device__ __forceinline__ int cls_of(int g, int l) {
    if (l < 1 || l > NLEV) return -1;
    if (g == 1) return l - 1;
    if (g == 2) return NLEV + (l - 1);
    return -1;
}

// ---------------- prep kernels ----------------

__global__ void deg_count_kernel(const int* __restrict__ dstv, int* __restrict__ degi, int E) {
    int i = blockIdx.x * blockDim.x + threadIdx.x;
    if (i < E) atomicAdd(&degi[dstv[i]], 1);
}

__global__ void deg_finalize_kernel(const int* __restrict__ degi, float* __restrict__ dis,
                                    float* __restrict__ inv, int n) {
    int i = blockIdx.x * blockDim.x + threadIdx.x;
    if (i < n) {
        float d = (float)degi[i] + 1.0f;
        dis[i] = rsqrtf(d);
        inv[i] = 1.0f / d;
    }
}

__global__ __launch_bounds__(1024) void prefix_kernel(const int* __restrict__ degi,
                                                      int* __restrict__ offs, int n) {
    __shared__ int part[1024];
    int t = threadIdx.x;
    int chunk = n / 1024;
    int base = t * chunk;
    int s = 0;
    for (int i = 0; i < chunk; i++) s += degi[base + i];
    part[t] = s;
    __syncthreads();
    for (int off = 1; off < 1024; off <<= 1) {
        int v = (t >= off) ? part[t - off] : 0;
        __syncthreads();
        part[t] += v;
        __syncthreads();
    }
    int excl = (t == 0) ? 0 : part[t - 1];
    for (int i = 0; i < chunk; i++) {
        int d = degi[base + i];
        offs[base + i] = excl;
        excl += d;
    }
    if (t == 1023) offs[n] = excl;
}

__global__ void csr_fill_kernel(const int* __restrict__ srcv, const int* __restrict__ dstv,
                                const int* __restrict__ offs, int* __restrict__ cursor,
                                int* __restrict__ csr_src, int E) {
    int i = blockIdx.x * blockDim.x + threadIdx.x;
    if (i >= E) return;
    int d = dstv[i];
    int pos = offs[d] + atomicAdd(&cursor[d], 1);
    csr_src[pos] = srcv[i];
}

// class lists + per-node packed (cls<<16)|idx lookup (clsidx pre-memset to -1)
__global__ __launch_bounds__(256) void build_node_lists_kernel(const int* __restrict__ gate,
                                                               const int* __restrict__ level,
                                                               int* __restrict__ nlist,
                                                               int* __restrict__ ncnt,
                                                               int* __restrict__ clsidx, int n) {
    __shared__ int lcnt[16];
    __shared__ int lbase[16];
    int t = threadIdx.x;
    int i = blockIdx.x * 256 + t;
    if (t < 16) lcnt[t] = 0;
    __syncthreads();
    int c = -1, lpos = 0;
    if (i < n) {
        c = cls_of(gate[i], level[i]);
        if (c >= 0) lpos = atomicAdd(&lcnt[c], 1);
    }
    __syncthreads();
    if (t < 16 && lcnt[t] > 0) lbase[t] = atomicAdd(&ncnt[t], lcnt[t]);
    __syncthreads();
    if (c >= 0) {
        int idx = lbase[c] + lpos;
        nlist[c * n + idx] = i;
        clsidx[i] = (c << 16) | idx;
    }
}

// ---------------- dense matmul: LDS-staged input tile, 32 rows/block ----------------
template <int BIAS>
__global__ __launch_bounds__(256) void mm_kernel(const float* __restrict__ in0,
                                                 const float* __restrict__ W,
                                                 const float* __restrict__ b,
                                                 float* __restrict__ out, int n) {
    const int R = 32;
    __shared__ float tile[R * DIM];
    const size_t row0 = (size_t)blockIdx.x * R;
    for (int t = threadIdx.x; t < R * DIM / 4; t += 256)
        ((float4*)tile)[t] = ((const float4*)(in0 + row0 * DIM))[t];
    __syncthreads();
    const int g = threadIdx.x >> 7;   // row-half 0/1
    const int j = threadIdx.x & 127;  // output column
    float acc[16];
#pragma unroll
    for (int r = 0; r < 16; r++) acc[r] = 0.f;
    const float* tb = tile + (g * 16) * DIM;
    for (int k = 0; k < DIM; k += 4) {
        float w0 = W[(k + 0) * DIM + j];
        float w1 = W[(k + 1) * DIM + j];
        float w2 = W[(k + 2) * DIM + j];
        float w3 = W[(k + 3) * DIM + j];
#pragma unroll
        for (int r = 0; r < 16; r++) {
            const float4 a = *reinterpret_cast<const float4*>(tb + r * DIM + k);
            acc[r] = fmaf(a.x, w0, acc[r]);
            acc[r] = fmaf(a.y, w1, acc[r]);
            acc[r] = fmaf(a.z, w2, acc[r]);
            acc[r] = fmaf(a.w, w3, acc[r]);
        }
    }
    float bias = BIAS ? b[j] : 0.f;
#pragma unroll
    for (int r = 0; r < 16; r++) out[(row0 + g * 16 + r) * DIM + j] = acc[r] + bias;
}

// fused decoder matmul: zs = in0 @ Ws, zt = in0 @ Wt (shared tile stage)
__global__ __launch_bounds__(256) void mm2_kernel(const float* __restrict__ in0,
                                                  const float* __restrict__ Ws,
                                                  const float* __restrict__ Wt,
                                                  float* __restrict__ zs,
                                                  float* __restrict__ zt, int n) {
    const int R = 32;
    __shared__ float tile[R * DIM];
    const size_t row0 = (size_t)blockIdx.x * R;
    for (int t = threadIdx.x; t < R * DIM / 4; t += 256)
        ((float4*)tile)[t] = ((const float4*)(in0 + row0 * DIM))[t];
    __syncthreads();
    const int g = threadIdx.x >> 7;
    const int j = threadIdx.x & 127;
    float accs[16], acct[16];
#pragma unroll
    for (int r = 0; r < 16; r++) { accs[r] = 0.f; acct[r] = 0.f; }
    const float* tb = tile + (g * 16) * DIM;
    for (int k = 0; k < DIM; k += 2) {
        float s0 = Ws[(k + 0) * DIM + j];
        float s1 = Ws[(k + 1) * DIM + j];
        float t0 = Wt[(k + 0) * DIM + j];
        float t1 = Wt[(k + 1) * DIM + j];
#pragma unroll
        for (int r = 0; r < 16; r++) {
            const float2 a = *reinterpret_cast<const float2*>(tb + r * DIM + k);
            accs[r] = fmaf(a.x, s0, accs[r]);
            accs[r] = fmaf(a.y, s1, accs[r]);
            acct[r] = fmaf(a.x, t0, acct[r]);
            acct[r] = fmaf(a.y, t1, acct[r]);
        }
    }
#pragma unroll
    for (int r = 0; r < 16; r++) {
        zs[(row0 + g * 16 + r) * DIM + j] = accs[r];
        zt[(row0 + g * 16 + r) * DIM + j] = acct[r];
    }
}

// ---------------- GCN aggregate as gather ----------------
__global__ __launch_bounds__(256) void gcn_gather_kernel(const float* __restrict__ x,
                                                         const float* __restrict__ dis,
                                                         const float* __restrict__ inv,
                                                         const float* __restrict__ gb,
                                                         const int* __restrict__ offs,
                                                         const int* __restrict__ csr_src,
                                                         float* __restrict__ x2, int n) {
    int slot = threadIdx.x >> 7, j = threadIdx.x & 127;
    for (int node = blockIdx.x * 2 + slot; node < n; node += gridDim.x * 2) {
        float di = dis[node];
        float acc = inv[node] * x[(size_t)node * DIM + j] + gb[j];
        int e1 = offs[node + 1];
        for (int p = offs[node]; p < e1; p++) {
            int s = csr_src[p];
            acc += di * dis[s] * x[(size_t)s * DIM + j];
        }
        x2[(size_t)node * DIM + j] = acc;
    }
}

// ---------------- level-stage kernels: wave-per-node, W staged in LDS ----------------

// pack a 128x128 W into LDS as float2: W2[k*64+jl] = (W[k][jl], W[k][jl+64])
__device__ __forceinline__ void stage_w128(const float* __restrict__ W, float2* __restrict__ W2) {
    for (int t = threadIdx.x; t < 128 * 64; t += 256) {
        int k = t >> 6, jl = t & 63;
        W2[t] = make_float2(W[k * DIM + jl], W[k * DIM + jl + 64]);
    }
}

template <bool MERGE>
__device__ __forceinline__ const float* resolve_row(const float* __restrict__ base,
                                                    const float* __restrict__ tmp,
                                                    const int* __restrict__ clsidx,
                                                    int mcls, int s) {
    if (MERGE) {
        int cc = clsidx[s];
        if ((cc >> 16) == mcls) return tmp + (size_t)(cc & 0xFFFF) * DIM;
    }
    return base + (size_t)s * DIM;
}

// wave gathers sum over in-edges of relu(row(src) @ W2 + b); 2-edge unroll
template <bool MERGE>
__device__ __forceinline__ void gather_node(const float* __restrict__ hs,
                                            const float* __restrict__ tmp,
                                            const int* __restrict__ clsidx, int mcls,
                                            const float2* __restrict__ W2,
                                            float bj0, float bj1,
                                            const int* __restrict__ csr_src,
                                            int e0, int e1, int lane,
                                            float& acc0, float& acc1) {
    for (int p = e0; p < e1; p += 2) {
        const bool two = (p + 1 < e1);
        const int s0 = csr_src[p];
        const int s1 = two ? csr_src[p + 1] : s0;
        const float* r0 = resolve_row<MERGE>(hs, tmp, clsidx, mcls, s0);
        const float* r1 = resolve_row<MERGE>(hs, tmp, clsidx, mcls, s1);
        float a00 = r0[lane], a01 = r0[lane + 64];
        float a10 = r1[lane], a11 = r1[lane + 64];
        float m00 = bj0, m01 = bj1, m10 = bj0, m11 = bj1;
#pragma unroll 8
        for (int k = 0; k < 64; k++) {
            float2 w = W2[k * 64 + lane];
            float v0 = __shfl(a00, k, 64);
            float v1 = __shfl(a10, k, 64);
            m00 = fmaf(v0, w.x, m00); m01 = fmaf(v0, w.y, m01);
            m10 = fmaf(v1, w.x, m10); m11 = fmaf(v1, w.y, m11);
        }
#pragma unroll 8
        for (int k = 0; k < 64; k++) {
            float2 w = W2[(k + 64) * 64 + lane];
            float v0 = __shfl(a01, k, 64);
            float v1 = __shfl(a11, k, 64);
            m00 = fmaf(v0, w.x, m00); m01 = fmaf(v0, w.y, m01);
            m10 = fmaf(v1, w.x, m10); m11 = fmaf(v1, w.y, m11);
        }
        acc0 += fmaxf(m00, 0.f);
        acc1 += fmaxf(m01, 0.f);
        if (two) { acc0 += fmaxf(m10, 0.f); acc1 += fmaxf(m11, 0.f); }
    }
}

// AND stage: commit tmpN(cNp)->hs ; agg = gather(as_w, merged w/ tmpN) ;
//            tmpA[idx] = relu( cat[hs[node], agg] @ ua_w + ua_b )  (two-phase restage)
template <bool MERGE>
__global__ __launch_bounds__(256) void and_stage_kernel(
        float* __restrict__ hs, const float* __restrict__ tmpN, float* __restrict__ tmpA,
        const int* __restrict__ offs, const int* __restrict__ csr_src,
        const int* __restrict__ nlist, const int* __restrict__ ncnt,
        const int* __restrict__ clsidx,
        const float* __restrict__ as_w, const float* __restrict__ as_b,
        const float* __restrict__ ua_w, const float* __restrict__ ua_b,
        int cA, int cNp, int n) {
    __shared__ float2 W2[128 * 64];
    const int lane = threadIdx.x & 63;
    const int gslot = (blockIdx.x << 2) | (threadIdx.x >> 6);
    stage_w128(as_w, W2);  // LDS writes; commit below uses only global -> overlap ok
    if (MERGE) {
        const int cntp = min(ncnt[cNp], CAP);
        for (int idx = gslot; idx < cntp; idx += NSLOT) {
            const int node = nlist[cNp * n + idx];
            hs[(size_t)node * DIM + lane] = tmpN[(size_t)idx * DIM + lane];
            hs[(size_t)node * DIM + lane + 64] = tmpN[(size_t)idx * DIM + lane + 64];
        }
    }
    __syncthreads();
    const int cnt = min(ncnt[cA], CAP);
    const float bj_as0 = as_b[lane], bj_as1 = as_b[lane + 64];
    float ag0[2] = {0.f, 0.f}, ag1[2] = {0.f, 0.f};
    float h0[2], h1[2];
    int nd[2]; bool act[2];
#pragma unroll
    for (int it = 0; it < 2; it++) {
        const int idx = gslot + it * NSLOT;
        act[it] = idx < cnt;
        nd[it] = act[it] ? nlist[cA * n + idx] : 0;
        if (act[it])
            gather_node<MERGE>(hs, tmpN, clsidx, cNp, W2, bj_as0, bj_as1, csr_src,
                               offs[nd[it]], offs[nd[it] + 1], lane, ag0[it], ag1[it]);
        // cA rows are not written by anyone this kernel -> pre-update value, as required
        h0[it] = hs[(size_t)nd[it] * DIM + lane];
        h1[it] = hs[(size_t)nd[it] * DIM + lane + 64];
    }
    float u0[2], u1[2];
    u0[0] = ua_b[lane]; u1[0] = ua_b[lane + 64];
    u0[1] = u0[0]; u1[1] = u1[0];
    __syncthreads();
    stage_w128(ua_w, W2);  // rows 0..127 (hs half)
    __syncthreads();
#pragma unroll
    for (int it = 0; it < 2; it++) {
#pragma unroll 8
        for (int k = 0; k < 64; k++) {
            float2 w = W2[k * 64 + lane];
            float v = __shfl(h0[it], k, 64);
            u0[it] = fmaf(v, w.x, u0[it]); u1[it] = fmaf(v, w.y, u1[it]);
        }
#pragma unroll 8
        for (int k = 0; k < 64; k++) {
            float2 w = W2[(k + 64) * 64 + lane];
            float v = __shfl(h1[it], k, 64);
            u0[it] = fmaf(v, w.x, u0[it]); u1[it] = fmaf(v, w.y, u1[it]);
        }
    }
    __syncthreads();
    stage_w128(ua_w + 128 * DIM, W2);  // rows 128..255 (agg half)
    __syncthreads();
#pragma unroll
    for (int it = 0; it < 2; it++) {
#pragma unroll 8
        for (int k = 0; k < 64; k++) {
            float2 w = W2[k * 64 + lane];
            float v = __shfl(ag0[it], k, 64);
            u0[it] = fmaf(v, w.x, u0[it]); u1[it] = fmaf(v, w.y, u1[it]);
        }
#pragma unroll 8
        for (int k = 0; k < 64; k++) {
            float2 w = W2[(k + 64) * 64 + lane];
            float v = __shfl(ag1[it], k, 64);
            u0[it] = fmaf(v, w.x, u0[it]); u1[it] = fmaf(v, w.y, u1[it]);
        }
        if (act[it]) {
            const int idx = gslot + it * NSLOT;
            tmpA[(size_t)idx * DIM + lane] = fmaxf(u0[it], 0.f);
            tmpA[(size_t)idx * DIM + lane + 64] = fmaxf(u1[it], 0.f);
        }
    }
}

// NOT stage: commit tmpA(cA)->hs ; agg = gather(ns_w, merged w/ tmpA) ;
//            tmpN[idx] = tanh( agg @ un_w + un_b )
__global__ __launch_bounds__(256) void not_stage_kernel(
        float* __restrict__ hs, const float* __restrict__ tmpA, float* __restrict__ tmpN,
        const int* __restrict__ offs, const int* __restrict__ csr_src,
        const int* __restrict__ nlist, const int* __restrict__ ncnt,
        const int* __restrict__ clsidx,
        const float* __restrict__ ns_w, const float* __restrict__ ns_b,
        const float* __restrict__ un_w, const float* __restrict__ un_b,
        int cA, int cN, int n) {
    __shared__ float2 W2[128 * 64];
    const int lane = threadIdx.x & 63;
    const int gslot = (blockIdx.x << 2) | (threadIdx.x >> 6);
    stage_w128(ns_w, W2);
    {
        const int cntA = min(ncnt[cA], CAP);
        for (int idx = gslot; idx < cntA; idx += NSLOT) {
            const int node = nlist[cA * n + idx];
            hs[(size_t)node * DIM + lane] = tmpA[(size_t)idx * DIM + lane];
            hs[(size_t)node * DIM + lane + 64] = tmpA[(size_t)idx * DIM + lane + 64];
        }
    }
    __syncthreads();
    const int cnt = min(ncnt[cN], CAP);
    const float bj_ns0 = ns_b[lane], bj_ns1 = ns_b[lane + 64];
    float ag0[2] = {0.f, 0.f}, ag1[2] = {0.f, 0.f};
    int nd[2]; bool act[2];
#pragma unroll
    for (int it = 0; it < 2; it++) {
        const int idx = gslot + it * NSLOT;
        act[it] = idx < cnt;
        nd[it] = act[it] ? nlist[cN * n + idx] : 0;
        if (act[it])
            gather_node<true>(hs, tmpA, clsidx, cA, W2, bj_ns0, bj_ns1, csr_src,
                              offs[nd[it]], offs[nd[it] + 1], lane, ag0[it], ag1[it]);
    }
    float u0[2], u1[2];
    u0[0] = un_b[lane]; u1[0] = un_b[lane + 64];
    u0[1] = u0[0]; u1[1] = u1[0];
    __syncthreads();
    stage_w128(un_w, W2);
    __syncthreads();
#pragma unroll
    for (int it = 0; it < 2; it++) {
#pragma unroll 8
        for (int k = 0; k < 64; k++) {
            float2 w = W2[k * 64 + lane];
            float v = __shfl(ag0[it], k, 64);
            u0[it] = fmaf(v, w.x, u0[it]); u1[it] = fmaf(v, w.y, u1[it]);
        }
#pragma unroll 8
        for (int k = 0; k < 64; k++) {
            float2 w = W2[(k + 64) * 64 + lane];
            float v = __shfl(ag1[it], k, 64);
            u0[it] = fmaf(v, w.x, u0[it]); u1[it] = fmaf(v, w.y, u1[it]);
        }
        if (act[it]) {
            const int idx = gslot + it * NSLOT;
            tmpN[(size_t)idx * DIM + lane] = tanhf(u0[it]);
            tmpN[(size_t)idx * DIM + lane + 64] = tanhf(u1[it]);
        }
    }
}

// final commit of last level's tmpN -> hs
__global__ __launch_bounds__(256) void commit_kernel(float* __restrict__ hs,
                                                     const float* __restrict__ tmp,
                                                     const int* __restrict__ nlist,
                                                     const int* __restrict__ ncnt,
                                                     int c, int n) {
    const int lane = threadIdx.x & 63;
    const int gslot = (blockIdx.x << 2) | (threadIdx.x >> 6);
    const int cnt = min(ncnt[c], CAP);
    for (int idx = gslot; idx < cnt; idx += NSLOT) {
        const int node = nlist[c * n + idx];
        hs[(size_t)node * DIM + lane] = tmp[(size_t)idx * DIM + lane];
        hs[(size_t)node * DIM + lane + 64] = tmp[(size_t)idx * DIM + lane + 64];
    }
}

// ---------------- decoder as gather (wave per node, deterministic) ----------------
__global__ __launch_bounds__(256) void dec_gather_kernel(const float* __restrict__ zs,
                                                         const float* __restrict__ zt,
                                                         const int* __restrict__ offs,
                                                         const int* __restrict__ csr_src,
                                                         float* __restrict__ hf_out, int n) {
    int w = threadIdx.x >> 6, lane = threadIdx.x & 63;
    for (int node = blockIdx.x * 4 + w; node < n; node += gridDim.x * 4) {
        float b0 = zt[(size_t)node * DIM + lane];
        float b1 = zt[(size_t)node * DIM + 64 + lane];
        float acc0 = 0.f, acc1 = 0.f;
        int e1 = offs[node + 1];
        for (int p = offs[node]; p < e1; p++) {
            int s = csr_src[p];
            float a0 = zs[(size_t)s * DIM + lane];
            float a1 = zs[(size_t)s * DIM + 64 + lane];
            float pd = a0 * b0 + a1 * b1;
#pragma unroll
            for (int off = 32; off > 0; off >>= 1) pd += __shfl_xor(pd, off, 64);
            float wg = 1.f / (1.f + __expf(-pd));
            acc0 += wg * a0;
            acc1 += wg * a1;
        }
        hf_out[(size_t)node * DIM + lane] = acc0;
        hf_out[(size_t)node * DIM + 64 + lane] = acc1;
    }
}

extern "C" void kernel_launch(void* const* d_in, const int* in_sizes, int n_in,
                              void* d_out, int out_size, void* d_ws, size_t ws_size,
                              hipStream_t stream) {
    const float* hs_init = (const float*)d_in[0];
    const int* ei = (const int*)d_in[1];
    const int* gate = (const int*)d_in[2];
    const int* level = (const int*)d_in[3];
    const float* gcn_w = (const float*)d_in[4];
    const float* gcn_b = (const float*)d_in[5];
    const float* mu_w = (const float*)d_in[6];
    const float* mu_b = (const float*)d_in[7];
    // ls_w/ls_b (8,9) dead (eval mode); af/nf (14..17) dead (level-loop hf never feeds hs;
    // decoder rebuilds hf from hs alone).
    const float* as_w = (const float*)d_in[10];
    const float* as_b = (const float*)d_in[11];
    const float* ns_w = (const float*)d_in[12];
    const float* ns_b = (const float*)d_in[13];
    const float* ua_w = (const float*)d_in[18];
    const float* ua_b = (const float*)d_in[19];
    const float* un_w = (const float*)d_in[20];
    const float* un_b = (const float*)d_in[21];
    const float* dec_ws_w = (const float*)d_in[22];
    const float* dec_wt_w = (const float*)d_in[23];

    const int n = in_sizes[0] / DIM;  // 32768
    const int E = in_sizes[1] / 2;    // 65536
    const int* srcv = ei;
    const int* dstv = ei + E;

    float* hs = (float*)d_out;             // [n, DIM]
    float* hf_out = hs + (size_t)n * DIM;  // [n, DIM]

    char* wp = (char*)d_ws;
    float* x = (float*)wp;    wp += (size_t)n * DIM * 4;       // gcn tmp, later zs
    float* x2 = (float*)wp;   wp += (size_t)n * DIM * 4;       // gcn tmp, later zt
    float* tmpA = (float*)wp; wp += (size_t)CAP * DIM * 4;     // AND-update staging
    float* tmpN = (float*)wp; wp += (size_t)CAP * DIM * 4;     // NOT-update staging
    char* small0 = wp;
    int* degi = (int*)wp;   wp += (size_t)n * 4;
    int* cursor = (int*)wp; wp += (size_t)n * 4;
    int* ncnt = (int*)wp;   wp += 16 * 4;
    size_t small_bytes = (size_t)(wp - small0);
    int* offs = (int*)wp;    wp += (size_t)(n + 1) * 4;
    int* csr_src = (int*)wp; wp += (size_t)E * 4;
    int* nlist = (int*)wp;   wp += (size_t)16 * n * 4;
    int* clsidx = (int*)wp;  wp += (size_t)n * 4;
    float* dis = (float*)wp; wp += (size_t)n * 4;
    float* inv = (float*)wp; wp += (size_t)n * 4;

    hipMemsetAsync(small0, 0, small_bytes, stream);
    hipMemsetAsync(clsidx, 0xFF, (size_t)n * 4, stream);

    deg_count_kernel<<<(E + 255) / 256, 256, 0, stream>>>(dstv, degi, E);
    deg_finalize_kernel<<<(n + 255) / 256, 256, 0, stream>>>(degi, dis, inv, n);
    build_node_lists_kernel<<<(n + 255) / 256, 256, 0, stream>>>(gate, level, nlist, ncnt, clsidx, n);
    prefix_kernel<<<1, 1024, 0, stream>>>(degi, offs, n);
    csr_fill_kernel<<<(E + 255) / 256, 256, 0, stream>>>(srcv, dstv, offs, cursor, csr_src, E);

    // --- GCN encoder ---
    mm_kernel<0><<<n / 32, 256, 0, stream>>>(hs_init, gcn_w, nullptr, x, n);
    gcn_gather_kernel<<<2048, 256, 0, stream>>>(x, dis, inv, gcn_b, offs, csr_src, x2, n);
    mm_kernel<1><<<n / 32, 256, 0, stream>>>(x2, mu_w, mu_b, hs, n);  // hs = mu

    // --- level loop: 2 launches/level (fused commit+gather+update), 1 final commit ---
    for (int l = 1; l <= NLEV; l++) {
        const int cA = l - 1;
        const int cN = NLEV + l - 1;
        const int cNp = NLEV + l - 2;
        if (l == 1)
            and_stage_kernel<false><<<NB_STAGE, 256, 0, stream>>>(
                hs, tmpN, tmpA, offs, csr_src, nlist, ncnt, clsidx,
                as_w, as_b, ua_w, ua_b, cA, -9, n);
        else
            and_stage_kernel<true><<<NB_STAGE, 256, 0, stream>>>(
                hs, tmpN, tmpA, offs, csr_src, nlist, ncnt, clsidx,
                as_w, as_b, ua_w, ua_b, cA, cNp, n);
        not_stage_kernel<<<NB_STAGE, 256, 0, stream>>>(
            hs, tmpA, tmpN, offs, csr_src, nlist, ncnt, clsidx,
            ns_w, ns_b, un_w, un_b, cA, cN, n);
    }
    commit_kernel<<<NB_STAGE, 256, 0, stream>>>(hs, tmpN, nlist, ncnt, 2 * NLEV - 1, n);

    // --- decoder ---
    float* zs = x;
    float* zt = x2;
    mm2_kernel<<<n / 32, 256, 0, stream>>>(hs, dec_ws_w, dec_wt_w, zs, zt, n);
    dec_gather_kernel<<<2048, 256, 0, stream>>>(zs, zt, offs, csr_src, hf_out, n);
}

// Round 7
// 653.723 us; speedup vs baseline: 12.1533x; 1.2049x over previous
//
#include <hip/hip_runtime.h>

#define DIM 128
#define NLEV 8
#define NB_STAGE 512           // stage-kernel grid; 4 waves/block -> 2048 wave-slots
#define NSLOT (NB_STAGE * 4)
#define CAP (2 * NSLOT)        // max nodes per class handled (expected ~1213)

__device__ __forceinline__ int cls_of(int g, int l) {
    if (l < 1 || l > NLEV) return -1;
    if (g == 1) return l - 1;
    if (g == 2) return NLEV + (l - 1);
    return -1;
}

// ---------------- prep kernels ----------------

__global__ void deg_count_kernel(const int* __restrict__ dstv, int* __restrict__ degi, int E) {
    int i = blockIdx.x * blockDim.x + threadIdx.x;
    if (i < E) atomicAdd(&degi[dstv[i]], 1);
}

__global__ void deg_finalize_kernel(const int* __restrict__ degi, float* __restrict__ dis,
                                    float* __restrict__ inv, int n) {
    int i = blockIdx.x * blockDim.x + threadIdx.x;
    if (i < n) {
        float d = (float)degi[i] + 1.0f;
        dis[i] = rsqrtf(d);
        inv[i] = 1.0f / d;
    }
}

// ---- 3-kernel parallel exclusive scan: degi[0..n) -> offs[0..n] ----
__global__ __launch_bounds__(1024) void scan1_kernel(const int* __restrict__ degi,
                                                     int* __restrict__ offs,
                                                     int* __restrict__ bsum) {
    __shared__ int sh[1024];
    const int gid = blockIdx.x * 1024 + threadIdx.x;
    const int v = degi[gid];
    sh[threadIdx.x] = v;
    __syncthreads();
    for (int off = 1; off < 1024; off <<= 1) {
        int t = (threadIdx.x >= off) ? sh[threadIdx.x - off] : 0;
        __syncthreads();
        sh[threadIdx.x] += t;
        __syncthreads();
    }
    offs[gid] = sh[threadIdx.x] - v;  // exclusive within block
    if (threadIdx.x == 1023) bsum[blockIdx.x] = sh[1023];
}

__global__ void scan2_kernel(int* __restrict__ bsum, int nb) {
    const int lane = threadIdx.x & 63;
    const int orig = (lane < nb) ? bsum[lane] : 0;
    int v = orig;
#pragma unroll
    for (int off = 1; off < 64; off <<= 1) {
        int t = __shfl_up(v, off, 64);
        if (lane >= off) v += t;
    }
    if (lane < nb) bsum[lane] = v - orig;  // exclusive base per block
    if (lane == nb - 1) bsum[nb] = v;      // grand total
}

__global__ __launch_bounds__(1024) void scan3_kernel(int* __restrict__ offs,
                                                     const int* __restrict__ bsum, int n) {
    const int gid = blockIdx.x * 1024 + threadIdx.x;
    offs[gid] += bsum[blockIdx.x];
    if (gid == n - 1) offs[n] = bsum[gridDim.x];
}

__global__ void csr_fill_kernel(const int* __restrict__ srcv, const int* __restrict__ dstv,
                                const int* __restrict__ offs, int* __restrict__ cursor,
                                int* __restrict__ csr_src, int E) {
    int i = blockIdx.x * blockDim.x + threadIdx.x;
    if (i >= E) return;
    int d = dstv[i];
    int pos = offs[d] + atomicAdd(&cursor[d], 1);
    csr_src[pos] = srcv[i];
}

// class lists + per-node packed (cls<<16)|idx lookup (clsidx pre-memset to -1)
__global__ __launch_bounds__(256) void build_node_lists_kernel(const int* __restrict__ gate,
                                                               const int* __restrict__ level,
                                                               int* __restrict__ nlist,
                                                               int* __restrict__ ncnt,
                                                               int* __restrict__ clsidx, int n) {
    __shared__ int lcnt[16];
    __shared__ int lbase[16];
    int t = threadIdx.x;
    int i = blockIdx.x * 256 + t;
    if (t < 16) lcnt[t] = 0;
    __syncthreads();
    int c = -1, lpos = 0;
    if (i < n) {
        c = cls_of(gate[i], level[i]);
        if (c >= 0) lpos = atomicAdd(&lcnt[c], 1);
    }
    __syncthreads();
    if (t < 16 && lcnt[t] > 0) lbase[t] = atomicAdd(&ncnt[t], lcnt[t]);
    __syncthreads();
    if (c >= 0) {
        int idx = lbase[c] + lpos;
        nlist[c * n + idx] = i;
        clsidx[i] = (c << 16) | idx;
    }
}

// ---------------- dense matmul: LDS-staged input tile, 32 rows/block ----------------
template <int BIAS>
__global__ __launch_bounds__(256) void mm_kernel(const float* __restrict__ in0,
                                                 const float* __restrict__ W,
                                                 const float* __restrict__ b,
                                                 float* __restrict__ out, int n) {
    const int R = 32;
    __shared__ float tile[R * DIM];
    const size_t row0 = (size_t)blockIdx.x * R;
    for (int t = threadIdx.x; t < R * DIM / 4; t += 256)
        ((float4*)tile)[t] = ((const float4*)(in0 + row0 * DIM))[t];
    __syncthreads();
    const int g = threadIdx.x >> 7;   // row-half 0/1
    const int j = threadIdx.x & 127;  // output column
    float acc[16];
#pragma unroll
    for (int r = 0; r < 16; r++) acc[r] = 0.f;
    const float* tb = tile + (g * 16) * DIM;
    for (int k = 0; k < DIM; k += 4) {
        float w0 = W[(k + 0) * DIM + j];
        float w1 = W[(k + 1) * DIM + j];
        float w2 = W[(k + 2) * DIM + j];
        float w3 = W[(k + 3) * DIM + j];
#pragma unroll
        for (int r = 0; r < 16; r++) {
            const float4 a = *reinterpret_cast<const float4*>(tb + r * DIM + k);
            acc[r] = fmaf(a.x, w0, acc[r]);
            acc[r] = fmaf(a.y, w1, acc[r]);
            acc[r] = fmaf(a.z, w2, acc[r]);
            acc[r] = fmaf(a.w, w3, acc[r]);
        }
    }
    float bias = BIAS ? b[j] : 0.f;
#pragma unroll
    for (int r = 0; r < 16; r++) out[(row0 + g * 16 + r) * DIM + j] = acc[r] + bias;
}

// fused decoder matmul: zs = in0 @ Ws, zt = in0 @ Wt (shared tile stage)
__global__ __launch_bounds__(256) void mm2_kernel(const float* __restrict__ in0,
                                                  const float* __restrict__ Ws,
                                                  const float* __restrict__ Wt,
                                                  float* __restrict__ zs,
                                                  float* __restrict__ zt, int n) {
    const int R = 32;
    __shared__ float tile[R * DIM];
    const size_t row0 = (size_t)blockIdx.x * R;
    for (int t = threadIdx.x; t < R * DIM / 4; t += 256)
        ((float4*)tile)[t] = ((const float4*)(in0 + row0 * DIM))[t];
    __syncthreads();
    const int g = threadIdx.x >> 7;
    const int j = threadIdx.x & 127;
    float accs[16], acct[16];
#pragma unroll
    for (int r = 0; r < 16; r++) { accs[r] = 0.f; acct[r] = 0.f; }
    const float* tb = tile + (g * 16) * DIM;
    for (int k = 0; k < DIM; k += 2) {
        float s0 = Ws[(k + 0) * DIM + j];
        float s1 = Ws[(k + 1) * DIM + j];
        float t0 = Wt[(k + 0) * DIM + j];
        float t1 = Wt[(k + 1) * DIM + j];
#pragma unroll
        for (int r = 0; r < 16; r++) {
            const float2 a = *reinterpret_cast<const float2*>(tb + r * DIM + k);
            accs[r] = fmaf(a.x, s0, accs[r]);
            accs[r] = fmaf(a.y, s1, accs[r]);
            acct[r] = fmaf(a.x, t0, acct[r]);
            acct[r] = fmaf(a.y, t1, acct[r]);
        }
    }
#pragma unroll
    for (int r = 0; r < 16; r++) {
        zs[(row0 + g * 16 + r) * DIM + j] = accs[r];
        zt[(row0 + g * 16 + r) * DIM + j] = acct[r];
    }
}

// ---------------- GCN aggregate as gather ----------------
__global__ __launch_bounds__(256) void gcn_gather_kernel(const float* __restrict__ x,
                                                         const float* __restrict__ dis,
                                                         const float* __restrict__ inv,
                                                         const float* __restrict__ gb,
                                                         const int* __restrict__ offs,
                                                         const int* __restrict__ csr_src,
                                                         float* __restrict__ x2, int n) {
    int slot = threadIdx.x >> 7, j = threadIdx.x & 127;
    for (int node = blockIdx.x * 2 + slot; node < n; node += gridDim.x * 2) {
        float di = dis[node];
        float acc = inv[node] * x[(size_t)node * DIM + j] + gb[j];
        int e1 = offs[node + 1];
        for (int p = offs[node]; p < e1; p++) {
            int s = csr_src[p];
            acc += di * dis[s] * x[(size_t)s * DIM + j];
        }
        x2[(size_t)node * DIM + j] = acc;
    }
}

// ---------------- level-stage kernels: wave-per-node, W staged in LDS ----------------

// pack a 128x128 W into LDS as float2: W2[k*64+jl] = (W[k][jl], W[k][jl+64])
__device__ __forceinline__ void stage_w128(const float* __restrict__ W, float2* __restrict__ W2) {
    for (int t = threadIdx.x; t < 128 * 64; t += 256) {
        int k = t >> 6, jl = t & 63;
        W2[t] = make_float2(W[k * DIM + jl], W[k * DIM + jl + 64]);
    }
}

template <bool MERGE>
__device__ __forceinline__ const float* resolve_row(const float* __restrict__ base,
                                                    const float* __restrict__ tmp,
                                                    const int* __restrict__ clsidx,
                                                    int mcls, int s) {
    if (MERGE) {
        int cc = clsidx[s];
        if ((cc >> 16) == mcls && (cc & 0xFFFF) < CAP) return tmp + (size_t)(cc & 0xFFFF) * DIM;
    }
    return base + (size_t)s * DIM;
}

// wave gathers sum over in-edges of relu(row(src) @ W2 + b); 2-edge unroll
template <bool MERGE>
__device__ __forceinline__ void gather_node(const float* __restrict__ hs,
                                            const float* __restrict__ tmp,
                                            const int* __restrict__ clsidx, int mcls,
                                            const float2* __restrict__ W2,
                                            float bj0, float bj1,
                                            const int* __restrict__ csr_src,
                                            int e0, int e1, int lane,
                                            float& acc0, float& acc1) {
    for (int p = e0; p < e1; p += 2) {
        const bool two = (p + 1 < e1);
        const int s0 = csr_src[p];
        const int s1 = two ? csr_src[p + 1] : s0;
        const float* r0 = resolve_row<MERGE>(hs, tmp, clsidx, mcls, s0);
        const float* r1 = resolve_row<MERGE>(hs, tmp, clsidx, mcls, s1);
        float a00 = r0[lane], a01 = r0[lane + 64];
        float a10 = r1[lane], a11 = r1[lane + 64];
        float m00 = bj0, m01 = bj1, m10 = bj0, m11 = bj1;
#pragma unroll 8
        for (int k = 0; k < 64; k++) {
            float2 w = W2[k * 64 + lane];
            float v0 = __shfl(a00, k, 64);
            float v1 = __shfl(a10, k, 64);
            m00 = fmaf(v0, w.x, m00); m01 = fmaf(v0, w.y, m01);
            m10 = fmaf(v1, w.x, m10); m11 = fmaf(v1, w.y, m11);
        }
#pragma unroll 8
        for (int k = 0; k < 64; k++) {
            float2 w = W2[(k + 64) * 64 + lane];
            float v0 = __shfl(a01, k, 64);
            float v1 = __shfl(a11, k, 64);
            m00 = fmaf(v0, w.x, m00); m01 = fmaf(v0, w.y, m01);
            m10 = fmaf(v1, w.x, m10); m11 = fmaf(v1, w.y, m11);
        }
        acc0 += fmaxf(m00, 0.f);
        acc1 += fmaxf(m01, 0.f);
        if (two) { acc0 += fmaxf(m10, 0.f); acc1 += fmaxf(m11, 0.f); }
    }
}

// AND stage: commit tmpN(cNp)->hs ; agg = gather(as_w, merged w/ tmpN) ;
//            tmpA[idx] = relu( cat[hs[node], agg] @ ua_w + ua_b )  (two-phase restage)
template <bool MERGE>
__global__ __launch_bounds__(256) void and_stage_kernel(
        float* __restrict__ hs, const float* __restrict__ tmpN, float* __restrict__ tmpA,
        const int* __restrict__ offs, const int* __restrict__ csr_src,
        const int* __restrict__ nlist, const int* __restrict__ ncnt,
        const int* __restrict__ clsidx,
        const float* __restrict__ as_w, const float* __restrict__ as_b,
        const float* __restrict__ ua_w, const float* __restrict__ ua_b,
        int cA, int cNp, int n) {
    const int cnt = min(ncnt[cA], CAP);
    const int cntp = MERGE ? min(ncnt[cNp], CAP) : 0;
    const int lim = max(cnt, cntp);
    if ((int)blockIdx.x * 4 >= lim) return;  // block-uniform early exit
    __shared__ float2 W2[128 * 64];
    const int lane = threadIdx.x & 63;
    const int gslot = (blockIdx.x << 2) | (threadIdx.x >> 6);
    stage_w128(as_w, W2);  // LDS writes; commit below uses only global -> overlap ok
    if (MERGE) {
        for (int idx = gslot; idx < cntp; idx += NSLOT) {
            const int node = nlist[cNp * n + idx];
            hs[(size_t)node * DIM + lane] = tmpN[(size_t)idx * DIM + lane];
            hs[(size_t)node * DIM + lane + 64] = tmpN[(size_t)idx * DIM + lane + 64];
        }
    }
    __syncthreads();
    const float bj_as0 = as_b[lane], bj_as1 = as_b[lane + 64];
    float ag0[2] = {0.f, 0.f}, ag1[2] = {0.f, 0.f};
    float h0[2] = {0.f, 0.f}, h1[2] = {0.f, 0.f};
    int nd[2]; bool act[2];
#pragma unroll
    for (int it = 0; it < 2; it++) {
        const int idx = gslot + it * NSLOT;
        act[it] = idx < cnt;
        nd[it] = act[it] ? nlist[cA * n + idx] : 0;
        if (act[it]) {
            gather_node<MERGE>(hs, tmpN, clsidx, cNp, W2, bj_as0, bj_as1, csr_src,
                               offs[nd[it]], offs[nd[it] + 1], lane, ag0[it], ag1[it]);
            // cA rows are not written by anyone this kernel -> pre-update value, as required
            h0[it] = hs[(size_t)nd[it] * DIM + lane];
            h1[it] = hs[(size_t)nd[it] * DIM + lane + 64];
        }
    }
    float u0[2], u1[2];
    u0[0] = ua_b[lane]; u1[0] = ua_b[lane + 64];
    u0[1] = u0[0]; u1[1] = u1[0];
    __syncthreads();
    stage_w128(ua_w, W2);  // rows 0..127 (hs half)
    __syncthreads();
#pragma unroll
    for (int it = 0; it < 2; it++) {
        if (!act[it]) continue;  // register-only loops, no barrier inside
#pragma unroll 8
        for (int k = 0; k < 64; k++) {
            float2 w = W2[k * 64 + lane];
            float v = __shfl(h0[it], k, 64);
            u0[it] = fmaf(v, w.x, u0[it]); u1[it] = fmaf(v, w.y, u1[it]);
        }
#pragma unroll 8
        for (int k = 0; k < 64; k++) {
            float2 w = W2[(k + 64) * 64 + lane];
            float v = __shfl(h1[it], k, 64);
            u0[it] = fmaf(v, w.x, u0[it]); u1[it] = fmaf(v, w.y, u1[it]);
        }
    }
    __syncthreads();
    stage_w128(ua_w + 128 * DIM, W2);  // rows 128..255 (agg half)
    __syncthreads();
#pragma unroll
    for (int it = 0; it < 2; it++) {
        if (!act[it]) continue;
#pragma unroll 8
        for (int k = 0; k < 64; k++) {
            float2 w = W2[k * 64 + lane];
            float v = __shfl(ag0[it], k, 64);
            u0[it] = fmaf(v, w.x, u0[it]); u1[it] = fmaf(v, w.y, u1[it]);
        }
#pragma unroll 8
        for (int k = 0; k < 64; k++) {
            float2 w = W2[(k + 64) * 64 + lane];
            float v = __shfl(ag1[it], k, 64);
            u0[it] = fmaf(v, w.x, u0[it]); u1[it] = fmaf(v, w.y, u1[it]);
        }
        const int idx = gslot + it * NSLOT;
        tmpA[(size_t)idx * DIM + lane] = fmaxf(u0[it], 0.f);
        tmpA[(size_t)idx * DIM + lane + 64] = fmaxf(u1[it], 0.f);
    }
}

// NOT stage: commit tmpA(cA)->hs ; agg = gather(ns_w, merged w/ tmpA) ;
//            tmpN[idx] = tanh( agg @ un_w + un_b )
__global__ __launch_bounds__(256) void not_stage_kernel(
        float* __restrict__ hs, const float* __restrict__ tmpA, float* __restrict__ tmpN,
        const int* __restrict__ offs, const int* __restrict__ csr_src,
        const int* __restrict__ nlist, const int* __restrict__ ncnt,
        const int* __restrict__ clsidx,
        const float* __restrict__ ns_w, const float* __restrict__ ns_b,
        const float* __restrict__ un_w, const float* __restrict__ un_b,
        int cA, int cN, int n) {
    const int cnt = min(ncnt[cN], CAP);
    const int cntA = min(ncnt[cA], CAP);
    const int lim = max(cnt, cntA);
    if ((int)blockIdx.x * 4 >= lim) return;
    __shared__ float2 W2[128 * 64];
    const int lane = threadIdx.x & 63;
    const int gslot = (blockIdx.x << 2) | (threadIdx.x >> 6);
    stage_w128(ns_w, W2);
    for (int idx = gslot; idx < cntA; idx += NSLOT) {
        const int node = nlist[cA * n + idx];
        hs[(size_t)node * DIM + lane] = tmpA[(size_t)idx * DIM + lane];
        hs[(size_t)node * DIM + lane + 64] = tmpA[(size_t)idx * DIM + lane + 64];
    }
    __syncthreads();
    const float bj_ns0 = ns_b[lane], bj_ns1 = ns_b[lane + 64];
    float ag0[2] = {0.f, 0.f}, ag1[2] = {0.f, 0.f};
    int nd[2]; bool act[2];
#pragma unroll
    for (int it = 0; it < 2; it++) {
        const int idx = gslot + it * NSLOT;
        act[it] = idx < cnt;
        nd[it] = act[it] ? nlist[cN * n + idx] : 0;
        if (act[it])
            gather_node<true>(hs, tmpA, clsidx, cA, W2, bj_ns0, bj_ns1, csr_src,
                              offs[nd[it]], offs[nd[it] + 1], lane, ag0[it], ag1[it]);
    }
    float u0[2], u1[2];
    u0[0] = un_b[lane]; u1[0] = un_b[lane + 64];
    u0[1] = u0[0]; u1[1] = u1[0];
    __syncthreads();
    stage_w128(un_w, W2);
    __syncthreads();
#pragma unroll
    for (int it = 0; it < 2; it++) {
        if (!act[it]) continue;
#pragma unroll 8
        for (int k = 0; k < 64; k++) {
            float2 w = W2[k * 64 + lane];
            float v = __shfl(ag0[it], k, 64);
            u0[it] = fmaf(v, w.x, u0[it]); u1[it] = fmaf(v, w.y, u1[it]);
        }
#pragma unroll 8
        for (int k = 0; k < 64; k++) {
            float2 w = W2[(k + 64) * 64 + lane];
            float v = __shfl(ag1[it], k, 64);
            u0[it] = fmaf(v, w.x, u0[it]); u1[it] = fmaf(v, w.y, u1[it]);
        }
        const int idx = gslot + it * NSLOT;
        tmpN[(size_t)idx * DIM + lane] = tanhf(u0[it]);
        tmpN[(size_t)idx * DIM + lane + 64] = tanhf(u1[it]);
    }
}

// final commit of last level's tmpN -> hs
__global__ __launch_bounds__(256) void commit_kernel(float* __restrict__ hs,
                                                     const float* __restrict__ tmp,
                                                     const int* __restrict__ nlist,
                                                     const int* __restrict__ ncnt,
                                                     int c, int n) {
    const int lane = threadIdx.x & 63;
    const int gslot = (blockIdx.x << 2) | (threadIdx.x >> 6);
    const int cnt = min(ncnt[c], CAP);
    for (int idx = gslot; idx < cnt; idx += NSLOT) {
        const int node = nlist[c * n + idx];
        hs[(size_t)node * DIM + lane] = tmp[(size_t)idx * DIM + lane];
        hs[(size_t)node * DIM + lane + 64] = tmp[(size_t)idx * DIM + lane + 64];
    }
}

// ---------------- decoder as gather (wave per node, deterministic) ----------------
__global__ __launch_bounds__(256) void dec_gather_kernel(const float* __restrict__ zs,
                                                         const float* __restrict__ zt,
                                                         const int* __restrict__ offs,
                                                         const int* __restrict__ csr_src,
                                                         float* __restrict__ hf_out, int n) {
    int w = threadIdx.x >> 6, lane = threadIdx.x & 63;
    for (int node = blockIdx.x * 4 + w; node < n; node += gridDim.x * 4) {
        float b0 = zt[(size_t)node * DIM + lane];
        float b1 = zt[(size_t)node * DIM + 64 + lane];
        float acc0 = 0.f, acc1 = 0.f;
        int e1 = offs[node + 1];
        for (int p = offs[node]; p < e1; p++) {
            int s = csr_src[p];
            float a0 = zs[(size_t)s * DIM + lane];
            float a1 = zs[(size_t)s * DIM + 64 + lane];
            float pd = a0 * b0 + a1 * b1;
#pragma unroll
            for (int off = 32; off > 0; off >>= 1) pd += __shfl_xor(pd, off, 64);
            float wg = 1.f / (1.f + __expf(-pd));
            acc0 += wg * a0;
            acc1 += wg * a1;
        }
        hf_out[(size_t)node * DIM + lane] = acc0;
        hf_out[(size_t)node * DIM + 64 + lane] = acc1;
    }
}

extern "C" void kernel_launch(void* const* d_in, const int* in_sizes, int n_in,
                              void* d_out, int out_size, void* d_ws, size_t ws_size,
                              hipStream_t stream) {
    const float* hs_init = (const float*)d_in[0];
    const int* ei = (const int*)d_in[1];
    const int* gate = (const int*)d_in[2];
    const int* level = (const int*)d_in[3];
    const float* gcn_w = (const float*)d_in[4];
    const float* gcn_b = (const float*)d_in[5];
    const float* mu_w = (const float*)d_in[6];
    const float* mu_b = (const float*)d_in[7];
    // ls_w/ls_b (8,9) dead (eval mode); af/nf (14..17) dead (level-loop hf never feeds hs;
    // decoder rebuilds hf from hs alone).
    const float* as_w = (const float*)d_in[10];
    const float* as_b = (const float*)d_in[11];
    const float* ns_w = (const float*)d_in[12];
    const float* ns_b = (const float*)d_in[13];
    const float* ua_w = (const float*)d_in[18];
    const float* ua_b = (const float*)d_in[19];
    const float* un_w = (const float*)d_in[20];
    const float* un_b = (const float*)d_in[21];
    const float* dec_ws_w = (const float*)d_in[22];
    const float* dec_wt_w = (const float*)d_in[23];

    const int n = in_sizes[0] / DIM;  // 32768
    const int E = in_sizes[1] / 2;    // 65536
    const int* srcv = ei;
    const int* dstv = ei + E;

    float* hs = (float*)d_out;             // [n, DIM]
    float* hf_out = hs + (size_t)n * DIM;  // [n, DIM]

    char* wp = (char*)d_ws;
    float* x = (float*)wp;    wp += (size_t)n * DIM * 4;       // gcn tmp, later zs
    float* x2 = (float*)wp;   wp += (size_t)n * DIM * 4;       // gcn tmp, later zt
    float* tmpA = (float*)wp; wp += (size_t)CAP * DIM * 4;     // AND-update staging
    float* tmpN = (float*)wp; wp += (size_t)CAP * DIM * 4;     // NOT-update staging
    char* small0 = wp;
    int* degi = (int*)wp;   wp += (size_t)n * 4;
    int* cursor = (int*)wp; wp += (size_t)n * 4;
    int* ncnt = (int*)wp;   wp += 16 * 4;
    size_t small_bytes = (size_t)(wp - small0);
    int* bsum = (int*)wp;    wp += 64 * 4;   // 32 block sums + total (no memset needed)
    int* offs = (int*)wp;    wp += (size_t)(n + 1) * 4;
    int* csr_src = (int*)wp; wp += (size_t)E * 4;
    int* nlist = (int*)wp;   wp += (size_t)16 * n * 4;
    int* clsidx = (int*)wp;  wp += (size_t)n * 4;
    float* dis = (float*)wp; wp += (size_t)n * 4;
    float* inv = (float*)wp; wp += (size_t)n * 4;

    hipMemsetAsync(small0, 0, small_bytes, stream);
    hipMemsetAsync(clsidx, 0xFF, (size_t)n * 4, stream);

    deg_count_kernel<<<(E + 255) / 256, 256, 0, stream>>>(dstv, degi, E);
    deg_finalize_kernel<<<(n + 255) / 256, 256, 0, stream>>>(degi, dis, inv, n);
    build_node_lists_kernel<<<(n + 255) / 256, 256, 0, stream>>>(gate, level, nlist, ncnt, clsidx, n);
    scan1_kernel<<<n / 1024, 1024, 0, stream>>>(degi, offs, bsum);
    scan2_kernel<<<1, 64, 0, stream>>>(bsum, n / 1024);
    scan3_kernel<<<n / 1024, 1024, 0, stream>>>(offs, bsum, n);
    csr_fill_kernel<<<(E + 255) / 256, 256, 0, stream>>>(srcv, dstv, offs, cursor, csr_src, E);

    // --- GCN encoder ---
    mm_kernel<0><<<n / 32, 256, 0, stream>>>(hs_init, gcn_w, nullptr, x, n);
    gcn_gather_kernel<<<4096, 256, 0, stream>>>(x, dis, inv, gcn_b, offs, csr_src, x2, n);
    mm_kernel<1><<<n / 32, 256, 0, stream>>>(x2, mu_w, mu_b, hs, n);  // hs = mu

    // --- level loop: 2 launches/level (fused commit+gather+update), 1 final commit ---
    for (int l = 1; l <= NLEV; l++) {
        const int cA = l - 1;
        const int cN = NLEV + l - 1;
        const int cNp = NLEV + l - 2;
        if (l == 1)
            and_stage_kernel<false><<<NB_STAGE, 256, 0, stream>>>(
                hs, tmpN, tmpA, offs, csr_src, nlist, ncnt, clsidx,
                as_w, as_b, ua_w, ua_b, cA, -9, n);
        else
            and_stage_kernel<true><<<NB_STAGE, 256, 0, stream>>>(
                hs, tmpN, tmpA, offs, csr_src, nlist, ncnt, clsidx,
                as_w, as_b, ua_w, ua_b, cA, cNp, n);
        not_stage_kernel<<<NB_STAGE, 256, 0, stream>>>(
            hs, tmpA, tmpN, offs, csr_src, nlist, ncnt, clsidx,
            ns_w, ns_b, un_w, un_b, cA, cN, n);
    }
    commit_kernel<<<NB_STAGE, 256, 0, stream>>>(hs, tmpN, nlist, ncnt, 2 * NLEV - 1, n);

    // --- decoder ---
    float* zs = x;
    float* zt = x2;
    mm2_kernel<<<n / 32, 256, 0, stream>>>(hs, dec_ws_w, dec_wt_w, zs, zt, n);
    dec_gather_kernel<<<4096, 256, 0, stream>>>(zs, zt, offs, csr_src, hf_out, n);
}